// Round 1
// baseline (1535.742 us; speedup 1.0000x reference)
//
#include <hip/hip_runtime.h>
#include <hip/hip_bf16.h>
#include <math.h>

// Problem constants
#define N      512           // batch
#define DIN    256           // input dim
#define LAM    0.43f

// ---------------------------------------------------------------------------
// ws layout (floats):
//   ws[0] = aesum          (f32 accumulator)
//   ws[1] = xdmax          (int-bits, atomicMax on non-negative floats)
//   ws[2] = topo           (f32 accumulator)
//   ws+64      : lat  [512*2]
//   ws+2048    : xd   [512*512]
//   ws+2048+262144 : ld [512*512]
// total ~2.01 MB — assumed <= ws_size
// ---------------------------------------------------------------------------

__global__ void init_kernel(float* __restrict__ ws) {
    if (threadIdx.x < 4) ws[threadIdx.x] = 0.f;
}

// Fused MLP: one block per batch row. 256 threads.
__global__ __launch_bounds__(256) void mlp_kernel(
    const float* __restrict__ x,
    const float* __restrict__ W1, const float* __restrict__ b1,
    const float* __restrict__ W2, const float* __restrict__ b2,
    const float* __restrict__ Wm, const float* __restrict__ bm,
    const float* __restrict__ W3, const float* __restrict__ b3,
    const float* __restrict__ W4, const float* __restrict__ b4,
    const float* __restrict__ W5, const float* __restrict__ b5,
    float* __restrict__ lat_out, float* __restrict__ aesum)
{
    __shared__ float xs[256];
    __shared__ float h1[128];
    __shared__ float h2[64];
    __shared__ float latv[2];
    __shared__ float h3[64];
    __shared__ float h4[128];
    __shared__ float red[4];

    const int tid = threadIdx.x;
    const int row = blockIdx.x;

    xs[tid] = x[(size_t)row * DIN + tid];
    __syncthreads();

    if (tid < 128) {
        float s = b1[tid];
        for (int k = 0; k < 256; ++k) s = fmaf(xs[k], W1[k * 128 + tid], s);
        h1[tid] = fmaxf(s, 0.f);
    }
    __syncthreads();

    if (tid < 64) {
        float s = b2[tid];
        for (int k = 0; k < 128; ++k) s = fmaf(h1[k], W2[k * 64 + tid], s);
        h2[tid] = fmaxf(s, 0.f);
    }
    __syncthreads();

    if (tid < 2) {
        float s = bm[tid];
        for (int k = 0; k < 64; ++k) s = fmaf(h2[k], Wm[k * 2 + tid], s);
        latv[tid] = s;
        lat_out[(size_t)row * 2 + tid] = s;
    }
    __syncthreads();

    if (tid < 64) {
        float s = b3[tid];
        s = fmaf(latv[0], W3[tid], s);
        s = fmaf(latv[1], W3[64 + tid], s);
        h3[tid] = fmaxf(s, 0.f);
    }
    __syncthreads();

    if (tid < 128) {
        float s = b4[tid];
        for (int k = 0; k < 64; ++k) s = fmaf(h3[k], W4[k * 128 + tid], s);
        h4[tid] = fmaxf(s, 0.f);
    }
    __syncthreads();

    float s = b5[tid];
    for (int k = 0; k < 128; ++k) s = fmaf(h4[k], W5[k * 256 + tid], s);
    float diff = xs[tid] - s;
    float a = diff * diff;

    #pragma unroll
    for (int m = 1; m < 64; m <<= 1) a += __shfl_xor(a, m, 64);
    if ((tid & 63) == 0) red[tid >> 6] = a;
    __syncthreads();
    if (tid == 0) atomicAdd(aesum, red[0] + red[1] + red[2] + red[3]);
}

// xd[i][j] = ||x_i - x_j||, diff-based (matches reference numerics), 64x64 tiles.
// Also produces global max via int-bits atomicMax (all values >= 0).
__global__ __launch_bounds__(256) void pdist_x_kernel(
    const float* __restrict__ x, float* __restrict__ xd, int* __restrict__ xdmax)
{
    __shared__ float As[32][65];
    __shared__ float Bs[32][65];
    __shared__ float red[4];

    const int tid = threadIdx.x;
    const int bi = blockIdx.x & 7, bj = blockIdx.x >> 3;
    const int i0 = bi * 64, j0 = bj * 64;
    const int ty = tid >> 4, tx = tid & 15;

    float acc[4][4];
    #pragma unroll
    for (int i = 0; i < 4; ++i)
        #pragma unroll
        for (int j = 0; j < 4; ++j) acc[i][j] = 0.f;

    for (int kk = 0; kk < DIN; kk += 32) {
        #pragma unroll
        for (int s = tid; s < 512; s += 256) {
            int r = s >> 3, c4 = (s & 7) << 2;
            float4 va = *(const float4*)(x + (size_t)(i0 + r) * DIN + kk + c4);
            As[c4 + 0][r] = va.x; As[c4 + 1][r] = va.y;
            As[c4 + 2][r] = va.z; As[c4 + 3][r] = va.w;
            float4 vb = *(const float4*)(x + (size_t)(j0 + r) * DIN + kk + c4);
            Bs[c4 + 0][r] = vb.x; Bs[c4 + 1][r] = vb.y;
            Bs[c4 + 2][r] = vb.z; Bs[c4 + 3][r] = vb.w;
        }
        __syncthreads();
        #pragma unroll 8
        for (int k = 0; k < 32; ++k) {
            float a[4], b[4];
            #pragma unroll
            for (int i = 0; i < 4; ++i) a[i] = As[k][ty + 16 * i];
            #pragma unroll
            for (int j = 0; j < 4; ++j) b[j] = Bs[k][tx + 16 * j];
            #pragma unroll
            for (int i = 0; i < 4; ++i)
                #pragma unroll
                for (int j = 0; j < 4; ++j) {
                    float d = a[i] - b[j];
                    acc[i][j] = fmaf(d, d, acc[i][j]);
                }
        }
        __syncthreads();
    }

    float lmax = 0.f;
    #pragma unroll
    for (int i = 0; i < 4; ++i)
        #pragma unroll
        for (int j = 0; j < 4; ++j) {
            float dd = sqrtf(acc[i][j]);
            int r = i0 + ty + 16 * i, c = j0 + tx + 16 * j;
            xd[(size_t)r * N + c] = dd;
            lmax = fmaxf(lmax, dd);
        }

    #pragma unroll
    for (int m = 32; m >= 1; m >>= 1) lmax = fmaxf(lmax, __shfl_xor(lmax, m, 64));
    if ((tid & 63) == 0) red[tid >> 6] = lmax;
    __syncthreads();
    if (tid == 0) {
        float mx = fmaxf(fmaxf(red[0], red[1]), fmaxf(red[2], red[3]));
        atomicMax(xdmax, __float_as_int(mx));
    }
}

// ld[i][j] = ||lat_i - lat_j||  (raw, scaling by 1/latent_norm deferred)
__global__ __launch_bounds__(256) void pdist_l_kernel(
    const float* __restrict__ lat, float* __restrict__ ld)
{
    const int i = blockIdx.x;
    const int j = blockIdx.y * 256 + threadIdx.x;
    float dx = lat[i * 2 + 0] - lat[j * 2 + 0];
    float dy = lat[i * 2 + 1] - lat[j * 2 + 1];
    ld[(size_t)i * N + j] = sqrtf(fmaf(dx, dx, dy * dy));
}

// Dense Prim's MST, one wave per block. Block 0: MST(xd), block 1: MST(ld).
// Accumulates per-edge (sD*D_e - sO*O_e)^2 into *topo.
__global__ __launch_bounds__(64) void mst_topo_kernel(
    const float* __restrict__ xd, const float* __restrict__ ld,
    const int* __restrict__ xdmax_bits, const float* __restrict__ latent_norm,
    float* __restrict__ topo)
{
    const int lane = threadIdx.x;
    const float* D; const float* O;
    if (blockIdx.x == 0) { D = xd; O = ld; }
    else                 { D = ld; O = xd; }

    float d[8];
    int   par[8];
    unsigned popped = 0;   // per-lane bitmask over its 8 vertices

    // init with distances to root vertex 0 (row 0)
    #pragma unroll
    for (int k = 0; k < 8; ++k) {
        d[k] = D[k * 64 + lane];
        par[k] = 0;
    }
    if (lane == 0) { popped |= 1u; d[0] = 0.f; }   // root in tree

    for (int it = 0; it < N - 1; ++it) {
        // lane-local argmin among unpopped vertices
        float bv = 1e30f; int bi2 = 0x7fffffff;
        #pragma unroll
        for (int k = 0; k < 8; ++k) {
            bool ok = !((popped >> k) & 1u);
            float v = ok ? d[k] : 1e30f;
            int   i = k * 64 + lane;
            if (v < bv) { bv = v; bi2 = i; }
        }
        // wave butterfly argmin (tie-break: smaller index) — all lanes converge
        #pragma unroll
        for (int m = 32; m >= 1; m >>= 1) {
            float ov = __shfl_xor(bv, m, 64);
            int   oi = __shfl_xor(bi2, m, 64);
            if (ov < bv || (ov == bv && oi < bi2)) { bv = ov; bi2 = oi; }
        }
        const int v = bi2;  // wave-uniform new tree vertex
        if ((v & 63) == lane) popped |= 1u << (v >> 6);  // d[k],par[k] frozen = MST edge

        // relax with row v
        const float* row = D + (size_t)v * N;
        #pragma unroll
        for (int k = 0; k < 8; ++k) {
            float w = row[k * 64 + lane];
            bool ok = !((popped >> k) & 1u);
            if (ok && w < d[k]) { d[k] = w; par[k] = v; }
        }
    }

    // contributions: every vertex except root contributes its MST edge (t, par[t])
    float xdm = __int_as_float(*xdmax_bits);
    float ln  = latent_norm[0];
    float sD, sO;
    if (blockIdx.x == 0) { sD = 1.f / xdm; sO = 1.f / ln; }
    else                 { sD = 1.f / ln;  sO = 1.f / xdm; }

    float acc = 0.f;
    #pragma unroll
    for (int k = 0; k < 8; ++k) {
        int t = k * 64 + lane;
        if (t != 0) {
            float de = d[k];
            float oe = O[(size_t)t * N + par[k]];
            float c = sD * de - sO * oe;
            acc = fmaf(c, c, acc);
        }
    }
    #pragma unroll
    for (int m = 32; m >= 1; m >>= 1) acc += __shfl_xor(acc, m, 64);
    if (lane == 0) atomicAdd(topo, acc);
}

__global__ void final_kernel(const float* __restrict__ ws, float* __restrict__ out)
{
    // ws[0]=aesum, ws[2]=topo
    out[0] = ws[0] * (1.f / (float)(N * DIN)) + (LAM * ws[2]) * (1.f / (float)N);
}

extern "C" void kernel_launch(void* const* d_in, const int* in_sizes, int n_in,
                              void* d_out, int out_size, void* d_ws, size_t ws_size,
                              hipStream_t stream) {
    const float* x   = (const float*)d_in[0];
    // d_in[1] = label (unused)
    const float* W1  = (const float*)d_in[2];
    const float* b1  = (const float*)d_in[3];
    const float* W2  = (const float*)d_in[4];
    const float* b2  = (const float*)d_in[5];
    const float* Wm  = (const float*)d_in[6];
    const float* bm  = (const float*)d_in[7];
    const float* W3  = (const float*)d_in[8];
    const float* b3  = (const float*)d_in[9];
    const float* W4  = (const float*)d_in[10];
    const float* b4  = (const float*)d_in[11];
    const float* W5  = (const float*)d_in[12];
    const float* b5  = (const float*)d_in[13];
    const float* latent_norm = (const float*)d_in[14];

    float* ws    = (float*)d_ws;
    float* aesum = ws + 0;
    int*   xdmax = (int*)(ws + 1);
    float* topo  = ws + 2;
    float* lat   = ws + 64;
    float* xd    = ws + 2048;
    float* ld    = xd + (size_t)N * N;

    init_kernel<<<1, 64, 0, stream>>>(ws);
    mlp_kernel<<<N, 256, 0, stream>>>(x, W1, b1, W2, b2, Wm, bm,
                                      W3, b3, W4, b4, W5, b5, lat, aesum);
    pdist_x_kernel<<<64, 256, 0, stream>>>(x, xd, xdmax);
    pdist_l_kernel<<<dim3(N, 2), 256, 0, stream>>>(lat, ld);
    mst_topo_kernel<<<2, 64, 0, stream>>>(xd, ld, xdmax, latent_norm, topo);
    final_kernel<<<1, 1, 0, stream>>>(ws, (float*)d_out);
}

// Round 2
// 468.535 us; speedup vs baseline: 3.2778x; 3.2778x over previous
//
#include <hip/hip_runtime.h>
#include <hip/hip_bf16.h>
#include <math.h>

// Problem constants
#define N      512           // batch
#define DIN    256           // input dim
#define LAM    0.43f

// ---------------------------------------------------------------------------
// ws layout (floats):
//   ws[0] = aesum          (f32 accumulator)
//   ws[1] = xdmax          (int-bits, atomicMax on non-negative floats)
//   ws[2] = topo           (f32 accumulator)
//   ws+64      : lat  [512*2]
//   ws+2048    : xd   [512*512]
//   ws+2048+262144 : ld [512*512]
// ---------------------------------------------------------------------------

__global__ void init_kernel(float* __restrict__ ws) {
    if (threadIdx.x < 4) ws[threadIdx.x] = 0.f;
}

// Fused MLP: one block per batch row. 256 threads.
__global__ __launch_bounds__(256) void mlp_kernel(
    const float* __restrict__ x,
    const float* __restrict__ W1, const float* __restrict__ b1,
    const float* __restrict__ W2, const float* __restrict__ b2,
    const float* __restrict__ Wm, const float* __restrict__ bm,
    const float* __restrict__ W3, const float* __restrict__ b3,
    const float* __restrict__ W4, const float* __restrict__ b4,
    const float* __restrict__ W5, const float* __restrict__ b5,
    float* __restrict__ lat_out, float* __restrict__ aesum)
{
    __shared__ float xs[256];
    __shared__ float h1[128];
    __shared__ float h2[64];
    __shared__ float latv[2];
    __shared__ float h3[64];
    __shared__ float h4[128];
    __shared__ float red[4];

    const int tid = threadIdx.x;
    const int row = blockIdx.x;

    xs[tid] = x[(size_t)row * DIN + tid];
    __syncthreads();

    if (tid < 128) {
        float s = b1[tid];
        for (int k = 0; k < 256; ++k) s = fmaf(xs[k], W1[k * 128 + tid], s);
        h1[tid] = fmaxf(s, 0.f);
    }
    __syncthreads();

    if (tid < 64) {
        float s = b2[tid];
        for (int k = 0; k < 128; ++k) s = fmaf(h1[k], W2[k * 64 + tid], s);
        h2[tid] = fmaxf(s, 0.f);
    }
    __syncthreads();

    if (tid < 2) {
        float s = bm[tid];
        for (int k = 0; k < 64; ++k) s = fmaf(h2[k], Wm[k * 2 + tid], s);
        latv[tid] = s;
        lat_out[(size_t)row * 2 + tid] = s;
    }
    __syncthreads();

    if (tid < 64) {
        float s = b3[tid];
        s = fmaf(latv[0], W3[tid], s);
        s = fmaf(latv[1], W3[64 + tid], s);
        h3[tid] = fmaxf(s, 0.f);
    }
    __syncthreads();

    if (tid < 128) {
        float s = b4[tid];
        for (int k = 0; k < 64; ++k) s = fmaf(h3[k], W4[k * 128 + tid], s);
        h4[tid] = fmaxf(s, 0.f);
    }
    __syncthreads();

    float s = b5[tid];
    for (int k = 0; k < 128; ++k) s = fmaf(h4[k], W5[k * 256 + tid], s);
    float diff = xs[tid] - s;
    float a = diff * diff;

    #pragma unroll
    for (int m = 1; m < 64; m <<= 1) a += __shfl_xor(a, m, 64);
    if ((tid & 63) == 0) red[tid >> 6] = a;
    __syncthreads();
    if (tid == 0) atomicAdd(aesum, red[0] + red[1] + red[2] + red[3]);
}

// xd[i][j] = ||x_i - x_j||, diff-based (matches reference numerics), 64x64 tiles.
__global__ __launch_bounds__(256) void pdist_x_kernel(
    const float* __restrict__ x, float* __restrict__ xd, int* __restrict__ xdmax)
{
    __shared__ float As[32][65];
    __shared__ float Bs[32][65];
    __shared__ float red[4];

    const int tid = threadIdx.x;
    const int bi = blockIdx.x & 7, bj = blockIdx.x >> 3;
    const int i0 = bi * 64, j0 = bj * 64;
    const int ty = tid >> 4, tx = tid & 15;

    float acc[4][4];
    #pragma unroll
    for (int i = 0; i < 4; ++i)
        #pragma unroll
        for (int j = 0; j < 4; ++j) acc[i][j] = 0.f;

    for (int kk = 0; kk < DIN; kk += 32) {
        #pragma unroll
        for (int s = tid; s < 512; s += 256) {
            int r = s >> 3, c4 = (s & 7) << 2;
            float4 va = *(const float4*)(x + (size_t)(i0 + r) * DIN + kk + c4);
            As[c4 + 0][r] = va.x; As[c4 + 1][r] = va.y;
            As[c4 + 2][r] = va.z; As[c4 + 3][r] = va.w;
            float4 vb = *(const float4*)(x + (size_t)(j0 + r) * DIN + kk + c4);
            Bs[c4 + 0][r] = vb.x; Bs[c4 + 1][r] = vb.y;
            Bs[c4 + 2][r] = vb.z; Bs[c4 + 3][r] = vb.w;
        }
        __syncthreads();
        #pragma unroll 8
        for (int k = 0; k < 32; ++k) {
            float a[4], b[4];
            #pragma unroll
            for (int i = 0; i < 4; ++i) a[i] = As[k][ty + 16 * i];
            #pragma unroll
            for (int j = 0; j < 4; ++j) b[j] = Bs[k][tx + 16 * j];
            #pragma unroll
            for (int i = 0; i < 4; ++i)
                #pragma unroll
                for (int j = 0; j < 4; ++j) {
                    float d = a[i] - b[j];
                    acc[i][j] = fmaf(d, d, acc[i][j]);
                }
        }
        __syncthreads();
    }

    float lmax = 0.f;
    #pragma unroll
    for (int i = 0; i < 4; ++i)
        #pragma unroll
        for (int j = 0; j < 4; ++j) {
            float dd = sqrtf(acc[i][j]);
            int r = i0 + ty + 16 * i, c = j0 + tx + 16 * j;
            xd[(size_t)r * N + c] = dd;
            lmax = fmaxf(lmax, dd);
        }

    #pragma unroll
    for (int m = 32; m >= 1; m >>= 1) lmax = fmaxf(lmax, __shfl_xor(lmax, m, 64));
    if ((tid & 63) == 0) red[tid >> 6] = lmax;
    __syncthreads();
    if (tid == 0) {
        float mx = fmaxf(fmaxf(red[0], red[1]), fmaxf(red[2], red[3]));
        atomicMax(xdmax, __float_as_int(mx));
    }
}

// ld[i][j] = ||lat_i - lat_j||  (raw, scaling by 1/latent_norm deferred)
__global__ __launch_bounds__(256) void pdist_l_kernel(
    const float* __restrict__ lat, float* __restrict__ ld)
{
    const int i = blockIdx.x;
    const int j = blockIdx.y * 256 + threadIdx.x;
    float dx = lat[i * 2 + 0] - lat[j * 2 + 0];
    float dy = lat[i * 2 + 1] - lat[j * 2 + 1];
    ld[(size_t)i * N + j] = sqrtf(fmaf(dx, dx, dy * dy));
}

// ---------------------------------------------------------------------------
// Dense Prim's MST, one wave per block. Block 0: MST(xd), block 1: MST(ld).
// Lane owns 8 CONSECUTIVE columns (lane*8..lane*8+7) -> float4 row loads.
// Cross-lane argmin via DPP (row_shr + row_bcast), ~2-4cy/step instead of
// ds_bpermute (~60-100cy/step). Key = (weight_bits<<32)|col_index packed as
// (hi,lo) pair -> exact smallest-index tie-break for free.
// ---------------------------------------------------------------------------

// one compare-select on an (hi,lo) u64 key pair
#define SELM(a, b)                                                       \
    {                                                                    \
        bool lt_ = (h[b] < h[a]) || (h[b] == h[a] && l[b] < l[a]);       \
        h[a] = lt_ ? h[b] : h[a];                                        \
        l[a] = lt_ ? l[b] : l[a];                                        \
    }

// one DPP min step on the running (h0,l0) key; ctrl must be a literal
#define DPP_STEP(ctrl)                                                                      \
    {                                                                                       \
        unsigned oh_ = (unsigned)__builtin_amdgcn_update_dpp((int)h0, (int)h0, ctrl, 0xf, 0xf, false); \
        unsigned ol_ = (unsigned)__builtin_amdgcn_update_dpp((int)l0, (int)l0, ctrl, 0xf, 0xf, false); \
        bool lt_ = (oh_ < h0) || (oh_ == h0 && ol_ < l0);                                   \
        h0 = lt_ ? oh_ : h0;                                                                \
        l0 = lt_ ? ol_ : l0;                                                                \
    }

__global__ __launch_bounds__(64) void mst_topo_kernel(
    const float* __restrict__ xd, const float* __restrict__ ld,
    const int* __restrict__ xdmax_bits, const float* __restrict__ latent_norm,
    float* __restrict__ topo)
{
    const int lane = threadIdx.x;
    const int base = lane << 3;     // first owned column
    const int lane2 = lane << 1;    // float4 index of first owned quad

    const float* D; const float* O;
    if (blockIdx.x == 0) { D = xd; O = ld; }
    else                 { D = ld; O = xd; }

    float d[8];
    int   par[8];
    unsigned popped = 0;   // per-lane bitmask over its 8 consecutive columns

    // init with distances to root vertex 0 (row 0), coalesced float4 loads
    {
        const float4* r4 = (const float4*)D;
        float4 a = r4[lane2], b = r4[lane2 + 1];
        d[0] = a.x; d[1] = a.y; d[2] = a.z; d[3] = a.w;
        d[4] = b.x; d[5] = b.y; d[6] = b.z; d[7] = b.w;
        #pragma unroll
        for (int k = 0; k < 8; ++k) par[k] = 0;
    }
    if (lane == 0) popped = 1u;   // root (col 0) in tree; d[0]==0 (diag)

    for (int it = 0; it < N - 1; ++it) {
        // --- lane-local tournament argmin over 8 owned columns ---
        unsigned h[8], l[8];
        #pragma unroll
        for (int k = 0; k < 8; ++k) {
            h[k] = ((popped >> k) & 1u) ? 0x7F800000u : __float_as_uint(d[k]);
            l[k] = (unsigned)(base + k);
        }
        SELM(0, 1) SELM(2, 3) SELM(4, 5) SELM(6, 7)
        SELM(0, 2) SELM(4, 6)
        SELM(0, 4)
        unsigned h0 = h[0], l0 = l[0];

        // --- wave argmin via DPP: intra-row shr 1/2/4/8, then bcast 15/31 ---
        DPP_STEP(0x111)  // row_shr:1
        DPP_STEP(0x112)  // row_shr:2
        DPP_STEP(0x114)  // row_shr:4
        DPP_STEP(0x118)  // row_shr:8
        DPP_STEP(0x142)  // row_bcast:15
        DPP_STEP(0x143)  // row_bcast:31
        const int v = __builtin_amdgcn_readlane((int)l0, 63);  // wave-uniform

        // freeze v's d/par = its MST edge
        if ((v >> 3) == lane) popped |= 1u << (v & 7);

        // --- relax with row v: two coalesced float4 loads per lane ---
        const float4* row4 = (const float4*)(D + (size_t)v * N);
        float4 ra = row4[lane2], rb = row4[lane2 + 1];
        float w[8] = {ra.x, ra.y, ra.z, ra.w, rb.x, rb.y, rb.z, rb.w};
        #pragma unroll
        for (int k = 0; k < 8; ++k) {
            bool ok = !((popped >> k) & 1u);
            if (ok && w[k] < d[k]) { d[k] = w[k]; par[k] = v; }
        }
    }

    // contributions: every vertex except root contributes its MST edge (t, par[t])
    float xdm = __int_as_float(*xdmax_bits);
    float ln  = latent_norm[0];
    float sD, sO;
    if (blockIdx.x == 0) { sD = 1.f / xdm; sO = 1.f / ln; }
    else                 { sD = 1.f / ln;  sO = 1.f / xdm; }

    float acc = 0.f;
    #pragma unroll
    for (int k = 0; k < 8; ++k) {
        int t = base + k;
        if (t != 0) {
            float de = d[k];
            float oe = O[(size_t)t * N + par[k]];
            float c = sD * de - sO * oe;
            acc = fmaf(c, c, acc);
        }
    }
    #pragma unroll
    for (int m = 32; m >= 1; m >>= 1) acc += __shfl_xor(acc, m, 64);
    if (lane == 0) atomicAdd(topo, acc);
}

__global__ void final_kernel(const float* __restrict__ ws, float* __restrict__ out)
{
    // ws[0]=aesum, ws[2]=topo
    out[0] = ws[0] * (1.f / (float)(N * DIN)) + (LAM * ws[2]) * (1.f / (float)N);
}

extern "C" void kernel_launch(void* const* d_in, const int* in_sizes, int n_in,
                              void* d_out, int out_size, void* d_ws, size_t ws_size,
                              hipStream_t stream) {
    const float* x   = (const float*)d_in[0];
    // d_in[1] = label (unused)
    const float* W1  = (const float*)d_in[2];
    const float* b1  = (const float*)d_in[3];
    const float* W2  = (const float*)d_in[4];
    const float* b2  = (const float*)d_in[5];
    const float* Wm  = (const float*)d_in[6];
    const float* bm  = (const float*)d_in[7];
    const float* W3  = (const float*)d_in[8];
    const float* b3  = (const float*)d_in[9];
    const float* W4  = (const float*)d_in[10];
    const float* b4  = (const float*)d_in[11];
    const float* W5  = (const float*)d_in[12];
    const float* b5  = (const float*)d_in[13];
    const float* latent_norm = (const float*)d_in[14];

    float* ws    = (float*)d_ws;
    float* aesum = ws + 0;
    int*   xdmax = (int*)(ws + 1);
    float* topo  = ws + 2;
    float* lat   = ws + 64;
    float* xd    = ws + 2048;
    float* ld    = xd + (size_t)N * N;

    init_kernel<<<1, 64, 0, stream>>>(ws);
    mlp_kernel<<<N, 256, 0, stream>>>(x, W1, b1, W2, b2, Wm, bm,
                                      W3, b3, W4, b4, W5, b5, lat, aesum);
    pdist_x_kernel<<<64, 256, 0, stream>>>(x, xd, xdmax);
    pdist_l_kernel<<<dim3(N, 2), 256, 0, stream>>>(lat, ld);
    mst_topo_kernel<<<2, 64, 0, stream>>>(xd, ld, xdmax, latent_norm, topo);
    final_kernel<<<1, 1, 0, stream>>>(ws, (float*)d_out);
}

// Round 3
// 350.339 us; speedup vs baseline: 4.3836x; 1.3374x over previous
//
#include <hip/hip_runtime.h>
#include <hip/hip_bf16.h>
#include <math.h>

// Problem constants
#define N      512           // batch
#define DIN    256           // input dim
#define LAM    0.43f

// ---------------------------------------------------------------------------
// ws layout (floats):
//   ws[8..71]    : pdist_x per-block max (64 blocks, raw/unscaled)
//   ws[80..81]   : mst topo partial per block (already scaled)
//   ws[128..639] : mlp per-row AE partial sums (512)
//   ws+1024      : lat [512*2]
//   ws+2048      : xd  [512*512]
//   ws+2048+262144 : ld [512*512]
// No atomics, no init kernel needed (every slot written unconditionally).
// ---------------------------------------------------------------------------

// Fused MLP: one block per batch row. 256 threads.
__global__ __launch_bounds__(256) void mlp_kernel(
    const float* __restrict__ x,
    const float* __restrict__ W1, const float* __restrict__ b1,
    const float* __restrict__ W2, const float* __restrict__ b2,
    const float* __restrict__ Wm, const float* __restrict__ bm,
    const float* __restrict__ W3, const float* __restrict__ b3,
    const float* __restrict__ W4, const float* __restrict__ b4,
    const float* __restrict__ W5, const float* __restrict__ b5,
    float* __restrict__ lat_out, float* __restrict__ ae_part)
{
    __shared__ float xs[256];
    __shared__ float h1[128];
    __shared__ float h2[64];
    __shared__ float latv[2];
    __shared__ float h3[64];
    __shared__ float h4[128];
    __shared__ float red[4];

    const int tid = threadIdx.x;
    const int row = blockIdx.x;

    xs[tid] = x[(size_t)row * DIN + tid];
    __syncthreads();

    if (tid < 128) {
        float s = b1[tid];
        for (int k = 0; k < 256; ++k) s = fmaf(xs[k], W1[k * 128 + tid], s);
        h1[tid] = fmaxf(s, 0.f);
    }
    __syncthreads();

    if (tid < 64) {
        float s = b2[tid];
        for (int k = 0; k < 128; ++k) s = fmaf(h1[k], W2[k * 64 + tid], s);
        h2[tid] = fmaxf(s, 0.f);
    }
    __syncthreads();

    if (tid < 2) {
        float s = bm[tid];
        for (int k = 0; k < 64; ++k) s = fmaf(h2[k], Wm[k * 2 + tid], s);
        latv[tid] = s;
        lat_out[(size_t)row * 2 + tid] = s;
    }
    __syncthreads();

    if (tid < 64) {
        float s = b3[tid];
        s = fmaf(latv[0], W3[tid], s);
        s = fmaf(latv[1], W3[64 + tid], s);
        h3[tid] = fmaxf(s, 0.f);
    }
    __syncthreads();

    if (tid < 128) {
        float s = b4[tid];
        for (int k = 0; k < 64; ++k) s = fmaf(h3[k], W4[k * 128 + tid], s);
        h4[tid] = fmaxf(s, 0.f);
    }
    __syncthreads();

    float s = b5[tid];
    for (int k = 0; k < 128; ++k) s = fmaf(h4[k], W5[k * 256 + tid], s);
    float diff = xs[tid] - s;
    float a = diff * diff;

    #pragma unroll
    for (int m = 1; m < 64; m <<= 1) a += __shfl_xor(a, m, 64);
    if ((tid & 63) == 0) red[tid >> 6] = a;
    __syncthreads();
    if (tid == 0) ae_part[row] = red[0] + red[1] + red[2] + red[3];
}

// xd[i][j] = ||x_i - x_j||, 64x64 tiles; per-block max -> ws[8+blockIdx].
__global__ __launch_bounds__(256) void pdist_x_kernel(
    const float* __restrict__ x, float* __restrict__ xd, float* __restrict__ blkmax)
{
    __shared__ float As[32][65];
    __shared__ float Bs[32][65];
    __shared__ float red[4];

    const int tid = threadIdx.x;
    const int bi = blockIdx.x & 7, bj = blockIdx.x >> 3;
    const int i0 = bi * 64, j0 = bj * 64;
    const int ty = tid >> 4, tx = tid & 15;

    float acc[4][4];
    #pragma unroll
    for (int i = 0; i < 4; ++i)
        #pragma unroll
        for (int j = 0; j < 4; ++j) acc[i][j] = 0.f;

    for (int kk = 0; kk < DIN; kk += 32) {
        #pragma unroll
        for (int s = tid; s < 512; s += 256) {
            int r = s >> 3, c4 = (s & 7) << 2;
            float4 va = *(const float4*)(x + (size_t)(i0 + r) * DIN + kk + c4);
            As[c4 + 0][r] = va.x; As[c4 + 1][r] = va.y;
            As[c4 + 2][r] = va.z; As[c4 + 3][r] = va.w;
            float4 vb = *(const float4*)(x + (size_t)(j0 + r) * DIN + kk + c4);
            Bs[c4 + 0][r] = vb.x; Bs[c4 + 1][r] = vb.y;
            Bs[c4 + 2][r] = vb.z; Bs[c4 + 3][r] = vb.w;
        }
        __syncthreads();
        #pragma unroll 8
        for (int k = 0; k < 32; ++k) {
            float a[4], b[4];
            #pragma unroll
            for (int i = 0; i < 4; ++i) a[i] = As[k][ty + 16 * i];
            #pragma unroll
            for (int j = 0; j < 4; ++j) b[j] = Bs[k][tx + 16 * j];
            #pragma unroll
            for (int i = 0; i < 4; ++i)
                #pragma unroll
                for (int j = 0; j < 4; ++j) {
                    float d = a[i] - b[j];
                    acc[i][j] = fmaf(d, d, acc[i][j]);
                }
        }
        __syncthreads();
    }

    float lmax = 0.f;
    #pragma unroll
    for (int i = 0; i < 4; ++i)
        #pragma unroll
        for (int j = 0; j < 4; ++j) {
            float dd = sqrtf(acc[i][j]);
            int r = i0 + ty + 16 * i, c = j0 + tx + 16 * j;
            xd[(size_t)r * N + c] = dd;
            lmax = fmaxf(lmax, dd);
        }

    #pragma unroll
    for (int m = 32; m >= 1; m >>= 1) lmax = fmaxf(lmax, __shfl_xor(lmax, m, 64));
    if ((tid & 63) == 0) red[tid >> 6] = lmax;
    __syncthreads();
    if (tid == 0)
        blkmax[blockIdx.x] = fmaxf(fmaxf(red[0], red[1]), fmaxf(red[2], red[3]));
}

// ld[i][j] = ||lat_i - lat_j||  (raw, scaling by 1/latent_norm deferred)
__global__ __launch_bounds__(256) void pdist_l_kernel(
    const float* __restrict__ lat, float* __restrict__ ld)
{
    const int i = blockIdx.x;
    const int j = blockIdx.y * 256 + threadIdx.x;
    float dx = lat[i * 2 + 0] - lat[j * 2 + 0];
    float dy = lat[i * 2 + 1] - lat[j * 2 + 1];
    ld[(size_t)i * N + j] = sqrtf(fmaf(dx, dx, dy * dy));
}

// ---------------------------------------------------------------------------
// Dense Prim's MST. Block 0: MST(xd), block 1: MST(ld). 1024 threads:
//   wave 0      : Prim (lane owns 8 consecutive columns, float4 row loads)
//   waves 1..15 : stream the whole D matrix once -> warms the LOCAL XCD L2,
//                 turning Prim's cold ~900cy row loads into ~220cy L2 hits.
// Wave argmin: value-only DPP fmin chain (6 steps), index recovered via
// ballot + ffs + readlane. No atomics; topo partial -> ws[80+blockIdx].
// ---------------------------------------------------------------------------

#define DPPMIN(ctrl)                                                                     \
    {                                                                                    \
        float o_ = __int_as_float(__builtin_amdgcn_update_dpp(                           \
            __float_as_int(bw), __float_as_int(bw), ctrl, 0xf, 0xf, false));             \
        bw = fminf(bw, o_);                                                              \
    }

__global__ __launch_bounds__(1024) void mst_topo_kernel(
    const float* __restrict__ xd, const float* __restrict__ ld,
    const float* __restrict__ latent_norm,
    const float* __restrict__ blkmax, float* __restrict__ topo_part)
{
    const int tid = threadIdx.x;
    const float* D; const float* O;
    if (blockIdx.x == 0) { D = xd; O = ld; }
    else                 { D = ld; O = xd; }

    if (tid >= 64) {
        // ---- helper waves: pull D into this XCD's L2 ----
        const float4* p4 = (const float4*)D;
        float4 s = make_float4(0.f, 0.f, 0.f, 0.f);
        #pragma unroll 8
        for (int i = tid - 64; i < (N * N / 4); i += 960) {
            float4 v = p4[i];
            s.x += v.x; s.y += v.y; s.z += v.z; s.w += v.w;
        }
        asm volatile("" :: "v"(s.x), "v"(s.y), "v"(s.z), "v"(s.w));
        return;
    }

    const int lane  = tid;
    const int base  = lane << 3;    // first owned column
    const int lane2 = lane << 1;    // float4 index of first owned quad
    const float INF = __int_as_float(0x7f800000);

    float d[8];
    int   par[8];
    unsigned popped = 0;

    {   // init with distances to root vertex 0 (row 0)
        const float4* r4 = (const float4*)D;
        float4 a = r4[lane2], b = r4[lane2 + 1];
        d[0] = a.x; d[1] = a.y; d[2] = a.z; d[3] = a.w;
        d[4] = b.x; d[5] = b.y; d[6] = b.z; d[7] = b.w;
        #pragma unroll
        for (int k = 0; k < 8; ++k) par[k] = 0;
    }
    if (lane == 0) popped = 1u;   // root (col 0)

    for (int it = 0; it < N - 1; ++it) {
        // --- masked values + lane-local min (fminf tree -> v_min3 fusion) ---
        float vk[8];
        #pragma unroll
        for (int k = 0; k < 8; ++k)
            vk[k] = ((popped >> k) & 1u) ? INF : d[k];
        float bw = fminf(fminf(fminf(vk[0], vk[1]), fminf(vk[2], vk[3])),
                         fminf(fminf(vk[4], vk[5]), fminf(vk[6], vk[7])));
        float bv = bw;   // this lane's local min (pre-reduce)

        // --- wave min via DPP: row_shr 1/2/4/8 then row_bcast 15/31 ---
        DPPMIN(0x111) DPPMIN(0x112) DPPMIN(0x114) DPPMIN(0x118)
        DPPMIN(0x142) DPPMIN(0x143)
        const float winval = __int_as_float(
            __builtin_amdgcn_readlane(__float_as_int(bw), 63));

        // --- recover argmin col: ballot lanes that hold winval ---
        unsigned kmask = 0;
        #pragma unroll
        for (int k = 0; k < 8; ++k)
            kmask |= (vk[k] == winval) ? (1u << k) : 0u;
        unsigned long long m = __ballot(kmask != 0);
        int src   = __ffsll(m) - 1;
        int mycol = base + (__ffs(kmask) - 1);
        const int v = __builtin_amdgcn_readlane(mycol, src);  // wave-uniform (SGPR)

        // freeze v's d/par = its MST edge
        if ((v >> 3) == lane) popped |= 1u << (v & 7);

        // --- relax with row v: two coalesced float4 loads per lane ---
        const float4* row4 = (const float4*)(D + (size_t)v * N);
        float4 ra = row4[lane2], rb = row4[lane2 + 1];
        float w[8] = {ra.x, ra.y, ra.z, ra.w, rb.x, rb.y, rb.z, rb.w};
        #pragma unroll
        for (int k = 0; k < 8; ++k) {
            bool ok = !((popped >> k) & 1u);
            if (ok && w[k] < d[k]) { d[k] = w[k]; par[k] = v; }
        }
    }

    // --- epilogue: reduce xd max (raw block maxima), then per-edge topo ---
    float mx = blkmax[lane];   // 64 values, one per lane
    #pragma unroll
    for (int mm = 32; mm >= 1; mm >>= 1) mx = fmaxf(mx, __shfl_xor(mx, mm, 64));
    const float xdm = mx;
    const float ln  = latent_norm[0];
    float sD, sO;
    if (blockIdx.x == 0) { sD = 1.f / xdm; sO = 1.f / ln; }
    else                 { sD = 1.f / ln;  sO = 1.f / xdm; }

    float acc = 0.f;
    #pragma unroll
    for (int k = 0; k < 8; ++k) {
        int t = base + k;
        if (t != 0) {
            float de = d[k];
            float oe = O[(size_t)t * N + par[k]];
            float c = sD * de - sO * oe;
            acc = fmaf(c, c, acc);
        }
    }
    #pragma unroll
    for (int mm = 32; mm >= 1; mm >>= 1) acc += __shfl_xor(acc, mm, 64);
    if (lane == 0) topo_part[blockIdx.x] = acc;
}

// Final: reduce 512 AE partials + 2 topo partials -> loss.
__global__ __launch_bounds__(512) void final_kernel(
    const float* __restrict__ ae_part, const float* __restrict__ topo_part,
    float* __restrict__ out)
{
    __shared__ float sred[8];
    const int tid = threadIdx.x;
    float a = ae_part[tid];
    #pragma unroll
    for (int m = 1; m < 64; m <<= 1) a += __shfl_xor(a, m, 64);
    if ((tid & 63) == 0) sred[tid >> 6] = a;
    __syncthreads();
    if (tid == 0) {
        float ae = 0.f;
        #pragma unroll
        for (int i = 0; i < 8; ++i) ae += sred[i];
        out[0] = ae * (1.f / (float)(N * DIN))
               + (LAM * (topo_part[0] + topo_part[1])) * (1.f / (float)N);
    }
}

extern "C" void kernel_launch(void* const* d_in, const int* in_sizes, int n_in,
                              void* d_out, int out_size, void* d_ws, size_t ws_size,
                              hipStream_t stream) {
    const float* x   = (const float*)d_in[0];
    // d_in[1] = label (unused)
    const float* W1  = (const float*)d_in[2];
    const float* b1  = (const float*)d_in[3];
    const float* W2  = (const float*)d_in[4];
    const float* b2  = (const float*)d_in[5];
    const float* Wm  = (const float*)d_in[6];
    const float* bm  = (const float*)d_in[7];
    const float* W3  = (const float*)d_in[8];
    const float* b3  = (const float*)d_in[9];
    const float* W4  = (const float*)d_in[10];
    const float* b4  = (const float*)d_in[11];
    const float* W5  = (const float*)d_in[12];
    const float* b5  = (const float*)d_in[13];
    const float* latent_norm = (const float*)d_in[14];

    float* ws       = (float*)d_ws;
    float* blkmax   = ws + 8;     // 64
    float* topo_prt = ws + 80;    // 2
    float* ae_part  = ws + 128;   // 512
    float* lat      = ws + 1024;  // 1024
    float* xd       = ws + 2048;  // 512*512
    float* ld       = xd + (size_t)N * N;

    mlp_kernel<<<N, 256, 0, stream>>>(x, W1, b1, W2, b2, Wm, bm,
                                      W3, b3, W4, b4, W5, b5, lat, ae_part);
    pdist_x_kernel<<<64, 256, 0, stream>>>(x, xd, blkmax);
    pdist_l_kernel<<<dim3(N, 2), 256, 0, stream>>>(lat, ld);
    mst_topo_kernel<<<2, 1024, 0, stream>>>(xd, ld, latent_norm, blkmax, topo_prt);
    final_kernel<<<1, 512, 0, stream>>>(ae_part, topo_prt, (float*)d_out);
}

// Round 5
// 335.449 us; speedup vs baseline: 4.5782x; 1.0444x over previous
//
#include <hip/hip_runtime.h>
#include <hip/hip_bf16.h>
#include <math.h>

// Problem constants
#define N      512           // batch
#define DIN    256           // input dim
#define LAM    0.43f
#define MAGIC  0x4D535431u

// ---------------------------------------------------------------------------
// ws layout (floats):
//   ws[4]  : ldready flag   (u32; poison 0xAAAAAAAA != MAGIC, no init needed)
//   ws[5]  : topo0ready flag
//   ws[6]  : topo0 value (f32 bits)
//   ws[8..71]    : pdist_x per-block max (64)
//   ws[128..639] : mlp per-row AE partials (512)
//   ws+1024      : lat [512*2]
//   ws+2048      : xd  [512*512]
//   ws+2048+262144 : ld [512*512]
//   ws+526336    : cand (2 blocks x 512 u64 = 2048 floats)
// total ~2.02 MB
// ---------------------------------------------------------------------------

// ============ kernel 1: fused MLP (blocks 0..511) + pdist_x (512..575) ======
__global__ __launch_bounds__(256) void fused_mlp_pdistx_kernel(
    const float* __restrict__ x,
    const float* __restrict__ W1, const float* __restrict__ b1,
    const float* __restrict__ W2, const float* __restrict__ b2,
    const float* __restrict__ Wm, const float* __restrict__ bm,
    const float* __restrict__ W3, const float* __restrict__ b3,
    const float* __restrict__ W4, const float* __restrict__ b4,
    const float* __restrict__ W5, const float* __restrict__ b5,
    float* __restrict__ lat_out, float* __restrict__ ae_part,
    float* __restrict__ xd, float* __restrict__ blkmax)
{
    const int tid = threadIdx.x;

    if (blockIdx.x < 512) {
        // ---------------- MLP path: one block per batch row ----------------
        __shared__ float xs[256];
        __shared__ float h1[128];
        __shared__ float h2[64];
        __shared__ float latv[2];
        __shared__ float h3[64];
        __shared__ float h4[128];
        __shared__ float red[4];

        const int row = blockIdx.x;
        xs[tid] = x[(size_t)row * DIN + tid];
        __syncthreads();

        if (tid < 128) {
            float s = b1[tid];
            for (int k = 0; k < 256; ++k) s = fmaf(xs[k], W1[k * 128 + tid], s);
            h1[tid] = fmaxf(s, 0.f);
        }
        __syncthreads();

        if (tid < 64) {
            float s = b2[tid];
            for (int k = 0; k < 128; ++k) s = fmaf(h1[k], W2[k * 64 + tid], s);
            h2[tid] = fmaxf(s, 0.f);
        }
        __syncthreads();

        if (tid < 2) {
            float s = bm[tid];
            for (int k = 0; k < 64; ++k) s = fmaf(h2[k], Wm[k * 2 + tid], s);
            latv[tid] = s;
            lat_out[(size_t)row * 2 + tid] = s;
        }
        __syncthreads();

        if (tid < 64) {
            float s = b3[tid];
            s = fmaf(latv[0], W3[tid], s);
            s = fmaf(latv[1], W3[64 + tid], s);
            h3[tid] = fmaxf(s, 0.f);
        }
        __syncthreads();

        if (tid < 128) {
            float s = b4[tid];
            for (int k = 0; k < 64; ++k) s = fmaf(h3[k], W4[k * 128 + tid], s);
            h4[tid] = fmaxf(s, 0.f);
        }
        __syncthreads();

        float s = b5[tid];
        for (int k = 0; k < 128; ++k) s = fmaf(h4[k], W5[k * 256 + tid], s);
        float diff = xs[tid] - s;
        float a = diff * diff;

        #pragma unroll
        for (int m = 1; m < 64; m <<= 1) a += __shfl_xor(a, m, 64);
        if ((tid & 63) == 0) red[tid >> 6] = a;
        __syncthreads();
        if (tid == 0) ae_part[row] = red[0] + red[1] + red[2] + red[3];
    } else {
        // ---------------- pdist_x path: 64 tile blocks ---------------------
        __shared__ float As[32][65];
        __shared__ float Bs[32][65];
        __shared__ float red2[4];

        const int bid = blockIdx.x - 512;
        const int bi = bid & 7, bj = bid >> 3;
        const int i0 = bi * 64, j0 = bj * 64;
        const int ty = tid >> 4, tx = tid & 15;

        float acc[4][4];
        #pragma unroll
        for (int i = 0; i < 4; ++i)
            #pragma unroll
            for (int j = 0; j < 4; ++j) acc[i][j] = 0.f;

        for (int kk = 0; kk < DIN; kk += 32) {
            #pragma unroll
            for (int s = tid; s < 512; s += 256) {
                int r = s >> 3, c4 = (s & 7) << 2;
                float4 va = *(const float4*)(x + (size_t)(i0 + r) * DIN + kk + c4);
                As[c4 + 0][r] = va.x; As[c4 + 1][r] = va.y;
                As[c4 + 2][r] = va.z; As[c4 + 3][r] = va.w;
                float4 vb = *(const float4*)(x + (size_t)(j0 + r) * DIN + kk + c4);
                Bs[c4 + 0][r] = vb.x; Bs[c4 + 1][r] = vb.y;
                Bs[c4 + 2][r] = vb.z; Bs[c4 + 3][r] = vb.w;
            }
            __syncthreads();
            #pragma unroll 8
            for (int k = 0; k < 32; ++k) {
                float a[4], b[4];
                #pragma unroll
                for (int i = 0; i < 4; ++i) a[i] = As[k][ty + 16 * i];
                #pragma unroll
                for (int j = 0; j < 4; ++j) b[j] = Bs[k][tx + 16 * j];
                #pragma unroll
                for (int i = 0; i < 4; ++i)
                    #pragma unroll
                    for (int j = 0; j < 4; ++j) {
                        float d = a[i] - b[j];
                        acc[i][j] = fmaf(d, d, acc[i][j]);
                    }
            }
            __syncthreads();
        }

        float lmax = 0.f;
        #pragma unroll
        for (int i = 0; i < 4; ++i)
            #pragma unroll
            for (int j = 0; j < 4; ++j) {
                float dd = sqrtf(acc[i][j]);
                int r = i0 + ty + 16 * i, c = j0 + tx + 16 * j;
                xd[(size_t)r * N + c] = dd;
                lmax = fmaxf(lmax, dd);
            }

        #pragma unroll
        for (int m = 32; m >= 1; m >>= 1) lmax = fmaxf(lmax, __shfl_xor(lmax, m, 64));
        if ((tid & 63) == 0) red2[tid >> 6] = lmax;
        __syncthreads();
        if (tid == 0)
            blkmax[bid] = fmaxf(fmaxf(red2[0], red2[1]), fmaxf(red2[2], red2[3]));
    }
}

// ============ kernel 2: Boruvka MST x2 + pdist_l (block1) + final ===========
// Block 0: MST(xd). Block 1: computes ld, publishes it, MST(ld), final loss.
// Boruvka: components at least halve per phase -> <=9 phases for N=512.
// Unique edge weights (random fp32 distances) => MST unique => same edge set
// as the reference's Kruskal. Mutual-pair hooking is cycle-free (weights
// strictly decrease along hook chains; only 2-cycles possible, broken by idx).
__global__ __launch_bounds__(1024) void mst_boruvka_kernel(
    const float* __restrict__ xd, float* __restrict__ ld,
    const float* __restrict__ lat, const float* __restrict__ latent_norm,
    const float* __restrict__ blkmax, const float* __restrict__ ae_part,
    float* __restrict__ wsf, unsigned long long* __restrict__ cand_all,
    float* __restrict__ out)
{
    __shared__ __align__(16) int comp[512];
    __shared__ float bestw[1024];
    __shared__ short bestj[1024];
    __shared__ int   tgt[512];
    __shared__ float ls_cw[512];
    __shared__ unsigned short ls_cu[512], ls_cvx[512];
    __shared__ unsigned short eu[512], ev[512];
    __shared__ float ew[512];
    __shared__ float latx[512], laty[512];
    __shared__ float s_red[16];
    __shared__ int s_ec, s_ncomp;
    __shared__ float s_xdm;

    const int tid = threadIdx.x;
    const int blk = blockIdx.x;
    const float INF = __int_as_float(0x7f800000);

    unsigned* ldready  = reinterpret_cast<unsigned*>(wsf + 4);
    unsigned* t0ready  = reinterpret_cast<unsigned*>(wsf + 5);
    unsigned* t0bits   = reinterpret_cast<unsigned*>(wsf + 6);
    unsigned long long* cand = cand_all + (size_t)blk * 512;

    // ---- block 1: compute ld from lat, publish to block 0 ----
    if (blk == 1) {
        for (int i = tid; i < 512; i += 1024) {
            latx[i] = lat[2 * i + 0];
            laty[i] = lat[2 * i + 1];
        }
        __syncthreads();
        for (int q = tid; q < (N * N / 4); q += 1024) {
            int i = q >> 7;
            int j = (q & 127) << 2;
            float xi = latx[i], yi = laty[i];
            float4 o;
            float dx0 = xi - latx[j + 0], dy0 = yi - laty[j + 0];
            float dx1 = xi - latx[j + 1], dy1 = yi - laty[j + 1];
            float dx2 = xi - latx[j + 2], dy2 = yi - laty[j + 2];
            float dx3 = xi - latx[j + 3], dy3 = yi - laty[j + 3];
            o.x = sqrtf(fmaf(dx0, dx0, dy0 * dy0));
            o.y = sqrtf(fmaf(dx1, dx1, dy1 * dy1));
            o.z = sqrtf(fmaf(dx2, dx2, dy2 * dy2));
            o.w = sqrtf(fmaf(dx3, dx3, dy3 * dy3));
            *(float4*)(ld + (size_t)i * N + j) = o;
        }
        __syncthreads();   // all ld stores drained (vmcnt) before release
        if (tid == 0)
            __hip_atomic_store(ldready, MAGIC, __ATOMIC_RELEASE,
                               __HIP_MEMORY_SCOPE_AGENT);
    }

    const float* Dm = (blk == 0) ? xd : ld;
    const float* Om = (blk == 0) ? ld : xd;

    // ---- xd max reduce (both blocks need it) ----
    if (tid < 64) {
        float mx = blkmax[tid];
        #pragma unroll
        for (int m = 32; m >= 1; m >>= 1) mx = fmaxf(mx, __shfl_xor(mx, m, 64));
        if (tid == 0) s_xdm = mx;
    }

    // ---- init ----
    if (tid < 512) comp[tid] = tid;
    if (tid == 0) { s_ec = 0; s_ncomp = 512; }
    __syncthreads();

    // ---- Boruvka phases ----
    for (int ph = 0; ph < 9; ++ph) {
        if (s_ncomp > 1) {
            // init candidates
            if (tid < 512) cand[tid] = ~0ULL;
            __syncthreads();

            // scan: vertex v = tid>>1, half h = tid&1 (cols [h*256, h*256+256))
            {
                const int v = tid >> 1, h = tid & 1;
                const int cv = comp[v];
                const int j0 = h * 256;
                const float4* rowp = (const float4*)(Dm + (size_t)v * N + j0);
                float bw = INF; int bj = -1;
                #pragma unroll 4
                for (int q = 0; q < 64; ++q) {
                    float4 f = rowp[q];
                    int4 c = *(const int4*)&comp[j0 + q * 4];
                    int j = j0 + q * 4;
                    if (c.x != cv && f.x < bw) { bw = f.x; bj = j; }
                    if (c.y != cv && f.y < bw) { bw = f.y; bj = j + 1; }
                    if (c.z != cv && f.z < bw) { bw = f.z; bj = j + 2; }
                    if (c.w != cv && f.w < bw) { bw = f.w; bj = j + 3; }
                }
                bestw[tid] = bw;
                bestj[tid] = (short)bj;
                __syncthreads();
                if (h == 0) {
                    float ow = bestw[tid + 1]; int oj = bestj[tid + 1];
                    if (ow < bw) { bw = ow; bj = oj; }
                    if (bj >= 0) {
                        unsigned long long pk =
                            ((unsigned long long)__float_as_uint(bw) << 32)
                            | ((unsigned)v << 9) | (unsigned)bj;
                        atomicMin(&cand[cv], pk);
                    }
                }
                __syncthreads();
            }

            // target pass: per root, decode candidate, find target component
            if (tid < 512) {
                int t_ = -1;
                if (comp[tid] == tid) {
                    unsigned long long c = atomicAdd(&cand[tid], 0ULL);  // L2 read
                    if ((unsigned)(c >> 32) != 0xFFFFFFFFu) {
                        unsigned uvtx = (unsigned)((c >> 9) & 0x1FF);
                        unsigned vvtx = (unsigned)(c & 0x1FF);
                        ls_cw[tid]  = __uint_as_float((unsigned)(c >> 32));
                        ls_cu[tid]  = (unsigned short)uvtx;
                        ls_cvx[tid] = (unsigned short)vvtx;
                        t_ = comp[vvtx];
                    }
                }
                tgt[tid] = t_;
            }
            __syncthreads();

            // hook pass: break mutual 2-cycles by index; record MST edges
            if (tid < 512) {
                int r = tid, s = tgt[r];
                if (s >= 0 && !(tgt[s] == r && r > s)) {
                    comp[r] = s;
                    int idx = atomicAdd(&s_ec, 1);
                    eu[idx] = ls_cu[r];
                    ev[idx] = ls_cvx[r];
                    ew[idx] = ls_cw[r];
                }
            }
            __syncthreads();

            // pointer doubling (depth <= 512 -> 9 rounds)
            for (int dd = 0; dd < 9; ++dd) {
                int c2 = 0;
                if (tid < 512) c2 = comp[comp[tid]];
                __syncthreads();
                if (tid < 512) comp[tid] = c2;
                __syncthreads();
            }

            if (tid == 0) s_ncomp = 512 - s_ec;
            __syncthreads();
        }
    }

    // ---- contributions ----
    const float xdm = s_xdm;
    const float lnv = latent_norm[0];
    float sD, sO;
    if (blk == 0) { sD = 1.f / xdm; sO = 1.f / lnv; }
    else          { sD = 1.f / lnv; sO = 1.f / xdm; }

    if (blk == 0) {
        // wait for ld to be published (agent-acquire invalidates L1/L2)
        if (tid == 0) {
            while (__hip_atomic_load(ldready, __ATOMIC_ACQUIRE,
                                     __HIP_MEMORY_SCOPE_AGENT) != MAGIC)
                __builtin_amdgcn_s_sleep(2);
        }
        __syncthreads();
    }

    const int ne = s_ec;   // 511
    float acc = 0.f;
    for (int i = tid; i < ne; i += 1024) {
        int u = eu[i], vv = ev[i];
        float de = ew[i];
        float oe = Om[(size_t)u * N + vv];
        float c = sD * de - sO * oe;
        acc = fmaf(c, c, acc);
    }
    #pragma unroll
    for (int m = 32; m >= 1; m >>= 1) acc += __shfl_xor(acc, m, 64);
    if ((tid & 63) == 0) s_red[tid >> 6] = acc;
    __syncthreads();

    if (blk == 0) {
        if (tid == 0) {
            float t0 = 0.f;
            #pragma unroll
            for (int i = 0; i < 16; ++i) t0 += s_red[i];
            __hip_atomic_store(t0bits, __float_as_uint(t0), __ATOMIC_RELAXED,
                               __HIP_MEMORY_SCOPE_AGENT);
            __hip_atomic_store(t0ready, MAGIC, __ATOMIC_RELEASE,
                               __HIP_MEMORY_SCOPE_AGENT);
        }
    } else {
        float topo1 = 0.f;
        if (tid == 0) {
            #pragma unroll
            for (int i = 0; i < 16; ++i) topo1 += s_red[i];
        }
        __syncthreads();
        // AE partial reduce (512 values from kernel 1)
        float a = (tid < 512) ? ae_part[tid] : 0.f;
        #pragma unroll
        for (int m = 32; m >= 1; m >>= 1) a += __shfl_xor(a, m, 64);
        if ((tid & 63) == 0) s_red[tid >> 6] = a;
        __syncthreads();
        if (tid == 0) {
            float ae = 0.f;
            #pragma unroll
            for (int i = 0; i < 16; ++i) ae += s_red[i];
            while (__hip_atomic_load(t0ready, __ATOMIC_ACQUIRE,
                                     __HIP_MEMORY_SCOPE_AGENT) != MAGIC)
                __builtin_amdgcn_s_sleep(2);
            float topo0 = __uint_as_float(
                __hip_atomic_load(t0bits, __ATOMIC_RELAXED,
                                  __HIP_MEMORY_SCOPE_AGENT));
            out[0] = ae * (1.f / (float)(N * DIN))
                   + (LAM * (topo0 + topo1)) * (1.f / (float)N);
        }
    }
}

extern "C" void kernel_launch(void* const* d_in, const int* in_sizes, int n_in,
                              void* d_out, int out_size, void* d_ws, size_t ws_size,
                              hipStream_t stream) {
    const float* x   = (const float*)d_in[0];
    // d_in[1] = label (unused)
    const float* W1  = (const float*)d_in[2];
    const float* b1  = (const float*)d_in[3];
    const float* W2  = (const float*)d_in[4];
    const float* b2  = (const float*)d_in[5];
    const float* Wm  = (const float*)d_in[6];
    const float* bm  = (const float*)d_in[7];
    const float* W3  = (const float*)d_in[8];
    const float* b3  = (const float*)d_in[9];
    const float* W4  = (const float*)d_in[10];
    const float* b4  = (const float*)d_in[11];
    const float* W5  = (const float*)d_in[12];
    const float* b5  = (const float*)d_in[13];
    const float* latent_norm = (const float*)d_in[14];

    float* ws       = (float*)d_ws;
    float* blkmax   = ws + 8;       // 64
    float* ae_part  = ws + 128;     // 512
    float* lat      = ws + 1024;    // 1024
    float* xd       = ws + 2048;    // 512*512
    float* ld       = xd + (size_t)N * N;
    unsigned long long* cand = (unsigned long long*)(ws + 526336);  // 2*512 u64

    fused_mlp_pdistx_kernel<<<576, 256, 0, stream>>>(
        x, W1, b1, W2, b2, Wm, bm, W3, b3, W4, b4, W5, b5,
        lat, ae_part, xd, blkmax);
    mst_boruvka_kernel<<<2, 1024, 0, stream>>>(
        xd, ld, lat, latent_norm, blkmax, ae_part, ws, cand, (float*)d_out);
}

// Round 6
// 174.567 us; speedup vs baseline: 8.7975x; 1.9216x over previous
//
#include <hip/hip_runtime.h>
#include <math.h>

// Problem constants
#define N      512
#define DIN    256
#define LAM    0.43f
#define MAGIC  0x4D535431u
#define NBW    64                       // worker blocks per MST
#define PAD(j) ((j) + (((j) >> 6) << 2))  // +4 words per 64: 2-way LDS banks

// ---------------------------------------------------------------------------
// ws word offsets (floats)
//   [4] ldready  [5] t0ready  [6] t0bits          (MAGIC-compared; 0xAA/0 safe)
//   [8..71]   blkmax          [128..639] ae_part
//   +1024 lat[1024]   +2048 xd[262144]   +264192 ld[262144]
//   +526336 cand u64[2][512]      +528384 gcomp u32[2][512]
//   +529408 gnc u32[2] (+pad)     +529424 dbar u32[2][16]
//   +529456 sbar u32[2][10][64]   +530736 ldbar u32[64]     end ~530800 (2.12MB)
// All inter-block flags are one-shot per launch and only compared == MAGIC,
// so they work whether ws starts as 0xAA poison or zeros. cand is explicitly
// reset by the leader before phase 0 (no poison assumption).
// ---------------------------------------------------------------------------
#define OFF_LDREADY 4
#define OFF_T0READY 5
#define OFF_T0BITS  6
#define OFF_BLKMAX  8
#define OFF_AEPART  128
#define OFF_LAT     1024
#define OFF_XD      2048
#define OFF_LD      (2048 + 262144)
#define OFF_CAND    526336
#define OFF_GCOMP   (OFF_CAND + 2048)
#define OFF_GNC     (OFF_GCOMP + 1024)
#define OFF_DBAR    (OFF_GNC + 16)
#define OFF_SBAR    (OFF_DBAR + 32)
#define OFF_LDBAR   (OFF_SBAR + 1280)

__device__ __forceinline__ unsigned ld_acq(unsigned* p) {
    return __hip_atomic_load(p, __ATOMIC_ACQUIRE, __HIP_MEMORY_SCOPE_AGENT);
}
__device__ __forceinline__ void st_rel(unsigned* p, unsigned v) {
    __hip_atomic_store(p, v, __ATOMIC_RELEASE, __HIP_MEMORY_SCOPE_AGENT);
}
__device__ __forceinline__ unsigned ld_rlx(unsigned* p) {
    return __hip_atomic_load(p, __ATOMIC_RELAXED, __HIP_MEMORY_SCOPE_AGENT);
}
__device__ __forceinline__ void st_rlx(unsigned* p, unsigned v) {
    __hip_atomic_store(p, v, __ATOMIC_RELAXED, __HIP_MEMORY_SCOPE_AGENT);
}
__device__ __forceinline__ unsigned long long ld64_rlx(unsigned long long* p) {
    return __hip_atomic_load(p, __ATOMIC_RELAXED, __HIP_MEMORY_SCOPE_AGENT);
}
__device__ __forceinline__ void st64_rlx(unsigned long long* p, unsigned long long v) {
    __hip_atomic_store(p, v, __ATOMIC_RELAXED, __HIP_MEMORY_SCOPE_AGENT);
}
__device__ __forceinline__ void spin_magic(unsigned* p) {
    while (ld_acq(p) != MAGIC) __builtin_amdgcn_s_sleep(1);
}

// ============ kernel 1: fused MLP (blocks 0..511) + pdist_x (512..575) ======
__global__ __launch_bounds__(256) void fused_mlp_pdistx_kernel(
    const float* __restrict__ x,
    const float* __restrict__ W1, const float* __restrict__ b1,
    const float* __restrict__ W2, const float* __restrict__ b2,
    const float* __restrict__ Wm, const float* __restrict__ bm,
    const float* __restrict__ W3, const float* __restrict__ b3,
    const float* __restrict__ W4, const float* __restrict__ b4,
    const float* __restrict__ W5, const float* __restrict__ b5,
    float* __restrict__ lat_out, float* __restrict__ ae_part,
    float* __restrict__ xd, float* __restrict__ blkmax)
{
    const int tid = threadIdx.x;

    if (blockIdx.x < 512) {
        __shared__ float xs[256];
        __shared__ float h1[128];
        __shared__ float h2[64];
        __shared__ float latv[2];
        __shared__ float h3[64];
        __shared__ float h4[128];
        __shared__ float red[4];

        const int row = blockIdx.x;
        xs[tid] = x[(size_t)row * DIN + tid];
        __syncthreads();

        if (tid < 128) {
            float s = b1[tid];
            for (int k = 0; k < 256; ++k) s = fmaf(xs[k], W1[k * 128 + tid], s);
            h1[tid] = fmaxf(s, 0.f);
        }
        __syncthreads();

        if (tid < 64) {
            float s = b2[tid];
            for (int k = 0; k < 128; ++k) s = fmaf(h1[k], W2[k * 64 + tid], s);
            h2[tid] = fmaxf(s, 0.f);
        }
        __syncthreads();

        if (tid < 2) {
            float s = bm[tid];
            for (int k = 0; k < 64; ++k) s = fmaf(h2[k], Wm[k * 2 + tid], s);
            latv[tid] = s;
            lat_out[(size_t)row * 2 + tid] = s;
        }
        __syncthreads();

        if (tid < 64) {
            float s = b3[tid];
            s = fmaf(latv[0], W3[tid], s);
            s = fmaf(latv[1], W3[64 + tid], s);
            h3[tid] = fmaxf(s, 0.f);
        }
        __syncthreads();

        if (tid < 128) {
            float s = b4[tid];
            for (int k = 0; k < 64; ++k) s = fmaf(h3[k], W4[k * 128 + tid], s);
            h4[tid] = fmaxf(s, 0.f);
        }
        __syncthreads();

        float s = b5[tid];
        for (int k = 0; k < 128; ++k) s = fmaf(h4[k], W5[k * 256 + tid], s);
        float diff = xs[tid] - s;
        float a = diff * diff;

        #pragma unroll
        for (int m = 1; m < 64; m <<= 1) a += __shfl_xor(a, m, 64);
        if ((tid & 63) == 0) red[tid >> 6] = a;
        __syncthreads();
        if (tid == 0) ae_part[row] = red[0] + red[1] + red[2] + red[3];
    } else {
        __shared__ float As[32][65];
        __shared__ float Bs[32][65];
        __shared__ float red2[4];

        const int bid = blockIdx.x - 512;
        const int bi = bid & 7, bj = bid >> 3;
        const int i0 = bi * 64, j0 = bj * 64;
        const int ty = tid >> 4, tx = tid & 15;

        float acc[4][4];
        #pragma unroll
        for (int i = 0; i < 4; ++i)
            #pragma unroll
            for (int j = 0; j < 4; ++j) acc[i][j] = 0.f;

        for (int kk = 0; kk < DIN; kk += 32) {
            #pragma unroll
            for (int s = tid; s < 512; s += 256) {
                int r = s >> 3, c4 = (s & 7) << 2;
                float4 va = *(const float4*)(x + (size_t)(i0 + r) * DIN + kk + c4);
                As[c4 + 0][r] = va.x; As[c4 + 1][r] = va.y;
                As[c4 + 2][r] = va.z; As[c4 + 3][r] = va.w;
                float4 vb = *(const float4*)(x + (size_t)(j0 + r) * DIN + kk + c4);
                Bs[c4 + 0][r] = vb.x; Bs[c4 + 1][r] = vb.y;
                Bs[c4 + 2][r] = vb.z; Bs[c4 + 3][r] = vb.w;
            }
            __syncthreads();
            #pragma unroll 8
            for (int k = 0; k < 32; ++k) {
                float a[4], b[4];
                #pragma unroll
                for (int i = 0; i < 4; ++i) a[i] = As[k][ty + 16 * i];
                #pragma unroll
                for (int j = 0; j < 4; ++j) b[j] = Bs[k][tx + 16 * j];
                #pragma unroll
                for (int i = 0; i < 4; ++i)
                    #pragma unroll
                    for (int j = 0; j < 4; ++j) {
                        float d = a[i] - b[j];
                        acc[i][j] = fmaf(d, d, acc[i][j]);
                    }
            }
            __syncthreads();
        }

        float lmax = 0.f;
        #pragma unroll
        for (int i = 0; i < 4; ++i)
            #pragma unroll
            for (int j = 0; j < 4; ++j) {
                float dd = sqrtf(acc[i][j]);
                int r = i0 + ty + 16 * i, c = j0 + tx + 16 * j;
                xd[(size_t)r * N + c] = dd;
                lmax = fmaxf(lmax, dd);
            }

        #pragma unroll
        for (int m = 32; m >= 1; m >>= 1) lmax = fmaxf(lmax, __shfl_xor(lmax, m, 64));
        if ((tid & 63) == 0) red2[tid >> 6] = lmax;
        __syncthreads();
        if (tid == 0)
            blkmax[bid] = fmaxf(fmaxf(red2[0], red2[1]), fmaxf(red2[2], red2[3]));
    }
}

// ============ kernel 2: multi-block Boruvka MST x2 =========================
// Grid = 128 blocks x 256 thr. Blocks [0..63] -> MST(xd), [64..127] -> MST(ld).
// Per MST: 64 worker blocks scan 8 rows each per phase, atomicMin u64 keyed
// (weight | row | col) into global cand[comp]; MAGIC-slot barrier; leader
// (local block 0) hooks + pointer-doubles comp in LDS, republishes, repeats.
// MST1 additionally computes ld up front (all-to-all barrier), MST0 waits on
// ldready only for its final edge-contribution reads. Leaders exchange topo
// via t0ready. <=9 phases (components at least halve; unique random weights).
__global__ __launch_bounds__(256) void mst_boruvka_kernel(
    const float* __restrict__ xd, float* __restrict__ ld,
    const float* __restrict__ lat, const float* __restrict__ latent_norm,
    const float* __restrict__ blkmax, const float* __restrict__ ae_part,
    float* __restrict__ wsf, float* __restrict__ out)
{
    __shared__ __align__(16) unsigned comp_p[544];   // padded scan copy
    __shared__ unsigned comp_a[512];                 // leader authoritative
    __shared__ unsigned long long cval[512];
    __shared__ int tgt[512];
    __shared__ unsigned short eu[512], ev[512];
    __shared__ float ew[512];
    __shared__ float latx[512], laty[512];
    __shared__ float s_red[4];
    __shared__ float s_xdm;
    __shared__ int s_ecnt;
    __shared__ unsigned s_nc;

    const int tid = threadIdx.x;
    const int blk = blockIdx.x;
    const int m   = blk >> 6;          // which MST
    const int wb  = blk & 63;          // worker index within MST
    const bool leader = (wb == 0);

    unsigned* ldready = (unsigned*)(wsf + OFF_LDREADY);
    unsigned* t0ready = (unsigned*)(wsf + OFF_T0READY);
    unsigned* t0bits  = (unsigned*)(wsf + OFF_T0BITS);
    unsigned long long* cand = (unsigned long long*)(wsf + OFF_CAND) + (size_t)m * 512;
    unsigned* gcomp = (unsigned*)(wsf + OFF_GCOMP) + (size_t)m * 512;
    unsigned* gnc   = (unsigned*)(wsf + OFF_GNC) + m;
    unsigned* dbar  = (unsigned*)(wsf + OFF_DBAR) + (size_t)m * 16;
    unsigned* sbar  = (unsigned*)(wsf + OFF_SBAR) + (size_t)m * 640;
    unsigned* ldbar = (unsigned*)(wsf + OFF_LDBAR);

    const float* Dm = m ? ld : xd;
    const float* Om = m ? xd : ld;

    // ---- MST1: compute ld, then all-to-all barrier among its 64 blocks ----
    if (m == 1) {
        for (int i = tid; i < 512; i += 256) {
            latx[i] = lat[2 * i + 0];
            laty[i] = lat[2 * i + 1];
        }
        __syncthreads();
        const int r0 = wb << 3;
        for (int q = tid; q < 1024; q += 256) {   // 8 rows x 128 float4
            int rr = r0 + (q >> 7);
            int j  = (q & 127) << 2;
            float xi = latx[rr], yi = laty[rr];
            float dx0 = xi - latx[j + 0], dy0 = yi - laty[j + 0];
            float dx1 = xi - latx[j + 1], dy1 = yi - laty[j + 1];
            float dx2 = xi - latx[j + 2], dy2 = yi - laty[j + 2];
            float dx3 = xi - latx[j + 3], dy3 = yi - laty[j + 3];
            float4 o;
            o.x = sqrtf(fmaf(dx0, dx0, dy0 * dy0));
            o.y = sqrtf(fmaf(dx1, dx1, dy1 * dy1));
            o.z = sqrtf(fmaf(dx2, dx2, dy2 * dy2));
            o.w = sqrtf(fmaf(dx3, dx3, dy3 * dy3));
            *(float4*)(ld + (size_t)rr * N + j) = o;
        }
        __syncthreads();                 // drains this block's ld stores
        if (tid == 0) st_rel(&ldbar[wb], MAGIC);
        if (tid < 64) spin_magic(&ldbar[tid]);   // all-to-all: everyone waits all
        __syncthreads();
        if (leader && tid == 0) st_rel(ldready, MAGIC);  // for MST0's epilogue
    }

    // ---- leader init: comp identity, edge count, cand reset, open phase 0 --
    if (leader) {
        for (int i = tid; i < 512; i += 256) comp_a[i] = (unsigned)i;
        if (tid == 0) s_ecnt = 0;
        for (int i = tid; i < 512; i += 256) st64_rlx(&cand[i], ~0ULL);
        __syncthreads();
        if (tid == 0) st_rel(&dbar[0], MAGIC);
    }
    if (tid == 0) spin_magic(&dbar[0]);
    __syncthreads();

    // ---- Boruvka phases ----
    for (int p = 0; p < 9; ++p) {
        if (p > 0) {
            if (tid == 0) { spin_magic(&dbar[p]); s_nc = ld_rlx(gnc); }
            __syncthreads();
            if (s_nc == 1) break;
            for (int i = tid; i < 512; i += 256)
                comp_p[PAD(i)] = ld_rlx(&gcomp[i]);
            __syncthreads();
        }

        // --- scan: this block's 8 rows; 32 threads per row, 16 cols each ---
        const int r  = (wb << 3) + (tid >> 5);
        const int c0 = (tid & 31) << 4;
        const unsigned cv = (p == 0) ? (unsigned)r : comp_p[PAD(r)];
        const float4* rp = (const float4*)(Dm + (size_t)r * N + c0);
        const int4*   cp = (const int4*)&comp_p[PAD(c0)];
        unsigned long long bk = ~0ULL;
        #pragma unroll
        for (int c = 0; c < 4; ++c) {
            float4 f = rp[c];
            int jb = c0 + 4 * c;
            unsigned j0c, j1c, j2c, j3c;
            if (p == 0) { j0c = jb; j1c = jb + 1; j2c = jb + 2; j3c = jb + 3; }
            else { int4 cc = cp[c]; j0c = cc.x; j1c = cc.y; j2c = cc.z; j3c = cc.w; }
            unsigned long long k;
            k = ((unsigned long long)__float_as_uint(f.x) << 18)
              | ((unsigned long long)r << 9) | (unsigned)(jb + 0);
            if (j0c != cv && k < bk) bk = k;
            k = ((unsigned long long)__float_as_uint(f.y) << 18)
              | ((unsigned long long)r << 9) | (unsigned)(jb + 1);
            if (j1c != cv && k < bk) bk = k;
            k = ((unsigned long long)__float_as_uint(f.z) << 18)
              | ((unsigned long long)r << 9) | (unsigned)(jb + 2);
            if (j2c != cv && k < bk) bk = k;
            k = ((unsigned long long)__float_as_uint(f.w) << 18)
              | ((unsigned long long)r << 9) | (unsigned)(jb + 3);
            if (j3c != cv && k < bk) bk = k;
        }
        #pragma unroll
        for (int mm = 1; mm <= 16; mm <<= 1) {
            unsigned long long o = __shfl_xor(bk, mm, 64);
            if (o < bk) bk = o;
        }
        if ((tid & 31) == 0 && bk != ~0ULL)
            atomicMin(&cand[cv], bk);
        __syncthreads();                 // drain all waves' atomics
        if (tid == 0) st_rel(&sbar[p * 64 + wb], MAGIC);

        // --- leader: gather candidates, hook, contract, republish ---
        if (leader) {
            if (tid < 64) spin_magic(&sbar[p * 64 + tid]);
            __syncthreads();
            for (int i = tid; i < 512; i += 256) cval[i] = ld64_rlx(&cand[i]);
            __syncthreads();
            for (int i = tid; i < 512; i += 256) {
                int t = -1;
                if (comp_a[i] == (unsigned)i && cval[i] != ~0ULL)
                    t = (int)comp_a[cval[i] & 511];
                tgt[i] = t;
            }
            __syncthreads();
            for (int i = tid; i < 512; i += 256) {
                int s = tgt[i];
                if (s >= 0 && !(tgt[s] == i && i > s)) {   // break mutual pairs
                    comp_a[i] = (unsigned)s;
                    int e = atomicAdd(&s_ecnt, 1);
                    unsigned long long c = cval[i];
                    eu[e] = (unsigned short)((c >> 9) & 511);
                    ev[e] = (unsigned short)(c & 511);
                    ew[e] = __uint_as_float((unsigned)(c >> 18));
                }
            }
            __syncthreads();
            for (int dd = 0; dd < 9; ++dd) {   // pointer doubling
                unsigned a = comp_a[comp_a[tid]];
                unsigned b = comp_a[comp_a[tid + 256]];
                __syncthreads();
                comp_a[tid] = a; comp_a[tid + 256] = b;
                __syncthreads();
            }
            const int nc = 512 - s_ecnt;
            for (int i = tid; i < 512; i += 256) {
                st_rlx(&gcomp[i], comp_a[i]);
                st64_rlx(&cand[i], ~0ULL);
            }
            if (tid == 0) st_rlx(gnc, (unsigned)nc);
            __syncthreads();             // drain republish stores
            if (tid == 0) st_rel(&dbar[p + 1], MAGIC);
            if (nc == 1) break;
        }
    }

    // ---- epilogue: leaders only ----
    if (leader) {
        if (tid < 64) {
            float mx = blkmax[tid];
            #pragma unroll
            for (int mm = 32; mm >= 1; mm >>= 1)
                mx = fmaxf(mx, __shfl_xor(mx, mm, 64));
            if (tid == 0) s_xdm = mx;
        }
        __syncthreads();
        const float xdm = s_xdm;
        const float lnv = latent_norm[0];
        const float sD = (m == 0) ? 1.f / xdm : 1.f / lnv;
        const float sO = (m == 0) ? 1.f / lnv : 1.f / xdm;

        if (m == 0) {                    // need ld for Om reads
            if (tid == 0) spin_magic(ldready);
            __syncthreads();
        }

        const int ne = s_ecnt;           // 511
        float acc = 0.f;
        for (int i = tid; i < ne; i += 256) {
            float de = ew[i];
            float oe = Om[(size_t)eu[i] * N + ev[i]];
            float c = sD * de - sO * oe;
            acc = fmaf(c, c, acc);
        }
        #pragma unroll
        for (int mm = 32; mm >= 1; mm >>= 1) acc += __shfl_xor(acc, mm, 64);
        if ((tid & 63) == 0) s_red[tid >> 6] = acc;
        __syncthreads();

        if (m == 0) {
            if (tid == 0) {
                float t0 = s_red[0] + s_red[1] + s_red[2] + s_red[3];
                st_rlx(t0bits, __float_as_uint(t0));
                st_rel(t0ready, MAGIC);
            }
        } else {
            float t1 = 0.f;
            if (tid == 0) t1 = s_red[0] + s_red[1] + s_red[2] + s_red[3];
            __syncthreads();             // s_red about to be reused
            float a = ae_part[tid] + ae_part[tid + 256];
            #pragma unroll
            for (int mm = 32; mm >= 1; mm >>= 1) a += __shfl_xor(a, mm, 64);
            if ((tid & 63) == 0) s_red[tid >> 6] = a;
            __syncthreads();
            if (tid == 0) {
                float ae = s_red[0] + s_red[1] + s_red[2] + s_red[3];
                spin_magic(t0ready);
                float t0 = __uint_as_float(ld_rlx(t0bits));
                out[0] = ae * (1.f / (float)(N * DIN))
                       + (LAM * (t0 + t1)) * (1.f / (float)N);
            }
        }
    }
}

extern "C" void kernel_launch(void* const* d_in, const int* in_sizes, int n_in,
                              void* d_out, int out_size, void* d_ws, size_t ws_size,
                              hipStream_t stream) {
    const float* x   = (const float*)d_in[0];
    // d_in[1] = label (unused)
    const float* W1  = (const float*)d_in[2];
    const float* b1  = (const float*)d_in[3];
    const float* W2  = (const float*)d_in[4];
    const float* b2  = (const float*)d_in[5];
    const float* Wm  = (const float*)d_in[6];
    const float* bm  = (const float*)d_in[7];
    const float* W3  = (const float*)d_in[8];
    const float* b3  = (const float*)d_in[9];
    const float* W4  = (const float*)d_in[10];
    const float* b4  = (const float*)d_in[11];
    const float* W5  = (const float*)d_in[12];
    const float* b5  = (const float*)d_in[13];
    const float* latent_norm = (const float*)d_in[14];

    float* ws      = (float*)d_ws;
    float* blkmax  = ws + OFF_BLKMAX;
    float* ae_part = ws + OFF_AEPART;
    float* lat     = ws + OFF_LAT;
    float* xd      = ws + OFF_XD;
    float* ld      = ws + OFF_LD;

    fused_mlp_pdistx_kernel<<<576, 256, 0, stream>>>(
        x, W1, b1, W2, b2, Wm, bm, W3, b3, W4, b4, W5, b5,
        lat, ae_part, xd, blkmax);
    mst_boruvka_kernel<<<128, 256, 0, stream>>>(
        xd, ld, lat, latent_norm, blkmax, ae_part, ws, (float*)d_out);
}

// Round 7
// 159.240 us; speedup vs baseline: 9.6442x; 1.0962x over previous
//
#include <hip/hip_runtime.h>
#include <math.h>

// Problem constants
#define N      512
#define DIN    256
#define LAM    0.43f
#define MAGIC  0x4D535431u
#define PAD(j) ((j) + (((j) >> 6) << 2))  // +4 words per 64: 2-way LDS banks

// ---------------------------------------------------------------------------
// ws word offsets (floats)
//   [4] ldready  [5] t0ready  [6] t0bits      (MAGIC-compared; 0xAA/0 safe)
//   [8..71] blkmax      [128..639] ae_part
//   +1024 lat[1024]  +2048 xd[262144]  +264192 ld[262144]
//   +526336 cand u64[2][9][512]  (one buffer PER PHASE -> no reset races;
//            explicitly initialized to ~0 before barrier 0)
//   +544768 bar  u32[2][10][64]  (MAGIC one-shot barrier slots)
// end ~545408 floats ~2.18 MB
// ---------------------------------------------------------------------------
#define OFF_LDREADY 4
#define OFF_T0READY 5
#define OFF_T0BITS  6
#define OFF_BLKMAX  8
#define OFF_AEPART  128
#define OFF_LAT     1024
#define OFF_XD      2048
#define OFF_LD      (2048 + 262144)
#define OFF_CAND    526336
#define OFF_BAR     (OFF_CAND + 18432)

__device__ __forceinline__ unsigned ld_acq(unsigned* p) {
    return __hip_atomic_load(p, __ATOMIC_ACQUIRE, __HIP_MEMORY_SCOPE_AGENT);
}
__device__ __forceinline__ void st_rel(unsigned* p, unsigned v) {
    __hip_atomic_store(p, v, __ATOMIC_RELEASE, __HIP_MEMORY_SCOPE_AGENT);
}
__device__ __forceinline__ unsigned ld_rlx(unsigned* p) {
    return __hip_atomic_load(p, __ATOMIC_RELAXED, __HIP_MEMORY_SCOPE_AGENT);
}
__device__ __forceinline__ unsigned long long ld64_rlx(unsigned long long* p) {
    return __hip_atomic_load(p, __ATOMIC_RELAXED, __HIP_MEMORY_SCOPE_AGENT);
}
__device__ __forceinline__ void st64_rlx(unsigned long long* p, unsigned long long v) {
    __hip_atomic_store(p, v, __ATOMIC_RELAXED, __HIP_MEMORY_SCOPE_AGENT);
}
__device__ __forceinline__ void spin_magic(unsigned* p) {
    while (ld_acq(p) != MAGIC) __builtin_amdgcn_s_sleep(1);
}

// ============ kernel 1: fused MLP (blocks 0..511) + pdist_x (512..575) ======
__global__ __launch_bounds__(256) void fused_mlp_pdistx_kernel(
    const float* __restrict__ x,
    const float* __restrict__ W1, const float* __restrict__ b1,
    const float* __restrict__ W2, const float* __restrict__ b2,
    const float* __restrict__ Wm, const float* __restrict__ bm,
    const float* __restrict__ W3, const float* __restrict__ b3,
    const float* __restrict__ W4, const float* __restrict__ b4,
    const float* __restrict__ W5, const float* __restrict__ b5,
    float* __restrict__ lat_out, float* __restrict__ ae_part,
    float* __restrict__ xd, float* __restrict__ blkmax)
{
    const int tid = threadIdx.x;

    if (blockIdx.x < 512) {
        __shared__ float xs[256];
        __shared__ float h1[128];
        __shared__ float h2[64];
        __shared__ float latv[2];
        __shared__ float h3[64];
        __shared__ float h4[128];
        __shared__ float red[4];

        const int row = blockIdx.x;
        xs[tid] = x[(size_t)row * DIN + tid];
        __syncthreads();

        if (tid < 128) {
            float s = b1[tid];
            for (int k = 0; k < 256; ++k) s = fmaf(xs[k], W1[k * 128 + tid], s);
            h1[tid] = fmaxf(s, 0.f);
        }
        __syncthreads();

        if (tid < 64) {
            float s = b2[tid];
            for (int k = 0; k < 128; ++k) s = fmaf(h1[k], W2[k * 64 + tid], s);
            h2[tid] = fmaxf(s, 0.f);
        }
        __syncthreads();

        if (tid < 2) {
            float s = bm[tid];
            for (int k = 0; k < 64; ++k) s = fmaf(h2[k], Wm[k * 2 + tid], s);
            latv[tid] = s;
            lat_out[(size_t)row * 2 + tid] = s;
        }
        __syncthreads();

        if (tid < 64) {
            float s = b3[tid];
            s = fmaf(latv[0], W3[tid], s);
            s = fmaf(latv[1], W3[64 + tid], s);
            h3[tid] = fmaxf(s, 0.f);
        }
        __syncthreads();

        if (tid < 128) {
            float s = b4[tid];
            for (int k = 0; k < 64; ++k) s = fmaf(h3[k], W4[k * 128 + tid], s);
            h4[tid] = fmaxf(s, 0.f);
        }
        __syncthreads();

        float s = b5[tid];
        for (int k = 0; k < 128; ++k) s = fmaf(h4[k], W5[k * 256 + tid], s);
        float diff = xs[tid] - s;
        float a = diff * diff;

        #pragma unroll
        for (int m = 1; m < 64; m <<= 1) a += __shfl_xor(a, m, 64);
        if ((tid & 63) == 0) red[tid >> 6] = a;
        __syncthreads();
        if (tid == 0) ae_part[row] = red[0] + red[1] + red[2] + red[3];
    } else {
        __shared__ float As[32][65];
        __shared__ float Bs[32][65];
        __shared__ float red2[4];

        const int bid = blockIdx.x - 512;
        const int bi = bid & 7, bj = bid >> 3;
        const int i0 = bi * 64, j0 = bj * 64;
        const int ty = tid >> 4, tx = tid & 15;

        float acc[4][4];
        #pragma unroll
        for (int i = 0; i < 4; ++i)
            #pragma unroll
            for (int j = 0; j < 4; ++j) acc[i][j] = 0.f;

        for (int kk = 0; kk < DIN; kk += 32) {
            #pragma unroll
            for (int s = tid; s < 512; s += 256) {
                int r = s >> 3, c4 = (s & 7) << 2;
                float4 va = *(const float4*)(x + (size_t)(i0 + r) * DIN + kk + c4);
                As[c4 + 0][r] = va.x; As[c4 + 1][r] = va.y;
                As[c4 + 2][r] = va.z; As[c4 + 3][r] = va.w;
                float4 vb = *(const float4*)(x + (size_t)(j0 + r) * DIN + kk + c4);
                Bs[c4 + 0][r] = vb.x; Bs[c4 + 1][r] = vb.y;
                Bs[c4 + 2][r] = vb.z; Bs[c4 + 3][r] = vb.w;
            }
            __syncthreads();
            #pragma unroll 8
            for (int k = 0; k < 32; ++k) {
                float a[4], b[4];
                #pragma unroll
                for (int i = 0; i < 4; ++i) a[i] = As[k][ty + 16 * i];
                #pragma unroll
                for (int j = 0; j < 4; ++j) b[j] = Bs[k][tx + 16 * j];
                #pragma unroll
                for (int i = 0; i < 4; ++i)
                    #pragma unroll
                    for (int j = 0; j < 4; ++j) {
                        float d = a[i] - b[j];
                        acc[i][j] = fmaf(d, d, acc[i][j]);
                    }
            }
            __syncthreads();
        }

        float lmax = 0.f;
        #pragma unroll
        for (int i = 0; i < 4; ++i)
            #pragma unroll
            for (int j = 0; j < 4; ++j) {
                float dd = sqrtf(acc[i][j]);
                int r = i0 + ty + 16 * i, c = j0 + tx + 16 * j;
                xd[(size_t)r * N + c] = dd;
                lmax = fmaxf(lmax, dd);
            }

        #pragma unroll
        for (int m = 32; m >= 1; m >>= 1) lmax = fmaxf(lmax, __shfl_xor(lmax, m, 64));
        if ((tid & 63) == 0) red2[tid >> 6] = lmax;
        __syncthreads();
        if (tid == 0)
            blkmax[bid] = fmaxf(fmaxf(red2[0], red2[1]), fmaxf(red2[2], red2[3]));
    }
}

// ============ kernel 2: decentralized multi-block Boruvka MST x2 ============
// Grid = 128 x 256. Blocks [0..63] -> MST(xd), [64..127] -> MST(ld).
// Per phase: 64 blocks scan 8 rows each, atomicMin u64 (w|row|col) into the
// PHASE-OWNED cand buffer; ONE all-to-all MAGIC barrier; then EVERY block
// redundantly gathers cand and does hook + pointer-doubling in its own LDS
// (identical deterministic results; comp never leaves LDS; no leader edge).
// MST1 computes ld before barrier 0 (which doubles as ld-complete barrier).
__global__ __launch_bounds__(256) void mst_boruvka_kernel(
    const float* __restrict__ xd, float* __restrict__ ld,
    const float* __restrict__ lat, const float* __restrict__ latent_norm,
    const float* __restrict__ blkmax, const float* __restrict__ ae_part,
    float* __restrict__ wsf, float* __restrict__ out)
{
    __shared__ unsigned comp_a[512];                 // authoritative (local)
    __shared__ __align__(16) unsigned comp_s[544];   // padded scan copy
    __shared__ unsigned long long cval[512];
    __shared__ int tgt[512];
    __shared__ unsigned short eu[512], ev[512];
    __shared__ float ew[512];
    __shared__ float latx[512], laty[512];
    __shared__ float s_red[4];
    __shared__ float s_xdm;
    __shared__ int s_ecnt;

    const int tid = threadIdx.x;
    const int blk = blockIdx.x;
    const int m   = blk >> 6;
    const int wb  = blk & 63;
    const bool leader = (wb == 0);

    unsigned* ldready = (unsigned*)(wsf + OFF_LDREADY);
    unsigned* t0ready = (unsigned*)(wsf + OFF_T0READY);
    unsigned* t0bits  = (unsigned*)(wsf + OFF_T0BITS);
    unsigned long long* candm =
        (unsigned long long*)(wsf + OFF_CAND) + (size_t)m * 9 * 512;
    unsigned* bar = (unsigned*)(wsf + OFF_BAR) + (size_t)m * 640;

    const float* Dm = m ? ld : xd;
    const float* Om = m ? xd : ld;

    // ---- MST1: compute ld rows (8 per block) before barrier 0 ----
    if (m == 1) {
        for (int i = tid; i < 512; i += 256) {
            latx[i] = lat[2 * i + 0];
            laty[i] = lat[2 * i + 1];
        }
        __syncthreads();
        const int r0 = wb << 3;
        for (int q = tid; q < 1024; q += 256) {   // 8 rows x 128 float4
            int rr = r0 + (q >> 7);
            int j  = (q & 127) << 2;
            float xi = latx[rr], yi = laty[rr];
            float dx0 = xi - latx[j + 0], dy0 = yi - laty[j + 0];
            float dx1 = xi - latx[j + 1], dy1 = yi - laty[j + 1];
            float dx2 = xi - latx[j + 2], dy2 = yi - laty[j + 2];
            float dx3 = xi - latx[j + 3], dy3 = yi - laty[j + 3];
            float4 o;
            o.x = sqrtf(fmaf(dx0, dx0, dy0 * dy0));
            o.y = sqrtf(fmaf(dx1, dx1, dy1 * dy1));
            o.z = sqrtf(fmaf(dx2, dx2, dy2 * dy2));
            o.w = sqrtf(fmaf(dx3, dx3, dy3 * dy3));
            *(float4*)(ld + (size_t)rr * N + j) = o;
        }
    }

    // ---- init this block's slice of all 9 phase cand buffers (72 u64) ----
    for (int i = tid; i < 72; i += 256)
        st64_rlx(&candm[(size_t)wb * 72 + i], ~0ULL);

    // ---- comp identity, local edge count ----
    for (int i = tid; i < 512; i += 256) {
        comp_a[i] = (unsigned)i;
        comp_s[PAD(i)] = (unsigned)i;
    }
    if (tid == 0) s_ecnt = 0;

    // ---- barrier 0: cand buffers ready + (m==1) ld complete ----
    __syncthreads();                       // drains vmem before flag
    if (tid == 0) st_rel(&bar[wb], MAGIC);
    if (tid < 64) spin_magic(&bar[tid]);
    __syncthreads();
    if (m == 1 && leader && tid == 0) st_rel(ldready, MAGIC);

    // ---- Boruvka phases (components at least halve -> <=9) ----
    int nc = 512;
    for (int p = 0; p < 9 && nc > 1; ++p) {
        unsigned long long* cand = candm + (size_t)p * 512;

        // --- scan: 8 rows/block, 32 threads/row, 16 cols/thread ---
        {
            const int r  = (wb << 3) + (tid >> 5);
            const int c0 = (tid & 31) << 4;
            const unsigned cv = comp_s[PAD(r)];
            const float4* rp = (const float4*)(Dm + (size_t)r * N + c0);
            unsigned long long bk = ~0ULL;
            #pragma unroll
            for (int c = 0; c < 4; ++c) {
                float4 f = rp[c];
                int jb = c0 + 4 * c;
                int4 cc = *(const int4*)&comp_s[PAD(jb)];
                unsigned long long k;
                k = ((unsigned long long)__float_as_uint(f.x) << 18)
                  | ((unsigned long long)r << 9) | (unsigned)(jb + 0);
                if ((unsigned)cc.x != cv && k < bk) bk = k;
                k = ((unsigned long long)__float_as_uint(f.y) << 18)
                  | ((unsigned long long)r << 9) | (unsigned)(jb + 1);
                if ((unsigned)cc.y != cv && k < bk) bk = k;
                k = ((unsigned long long)__float_as_uint(f.z) << 18)
                  | ((unsigned long long)r << 9) | (unsigned)(jb + 2);
                if ((unsigned)cc.z != cv && k < bk) bk = k;
                k = ((unsigned long long)__float_as_uint(f.w) << 18)
                  | ((unsigned long long)r << 9) | (unsigned)(jb + 3);
                if ((unsigned)cc.w != cv && k < bk) bk = k;
            }
            #pragma unroll
            for (int mm = 1; mm <= 16; mm <<= 1) {
                unsigned long long o = __shfl_xor(bk, mm, 64);
                if (o < bk) bk = o;
            }
            if ((tid & 31) == 0 && bk != ~0ULL)
                atomicMin(&cand[cv], bk);
        }

        // --- one all-to-all barrier: all atomicMins for phase p done ---
        __syncthreads();                   // drains this block's atomics
        if (tid == 0) st_rel(&bar[(p + 1) * 64 + wb], MAGIC);
        if (tid < 64) spin_magic(&bar[(p + 1) * 64 + tid]);
        __syncthreads();

        // --- every block: gather candidates, hook, contract (redundant) ---
        for (int i = tid; i < 512; i += 256) cval[i] = ld64_rlx(&cand[i]);
        __syncthreads();
        for (int i = tid; i < 512; i += 256) {
            int t = -1;
            if (comp_a[i] == (unsigned)i && cval[i] != ~0ULL)
                t = (int)comp_a[cval[i] & 511];
            tgt[i] = t;
        }
        __syncthreads();
        for (int i = tid; i < 512; i += 256) {
            int s = tgt[i];
            if (s >= 0 && !(tgt[s] == i && i > s)) {   // break mutual pairs
                comp_a[i] = (unsigned)s;
                int e = atomicAdd(&s_ecnt, 1);
                unsigned long long c = cval[i];
                eu[e] = (unsigned short)((c >> 9) & 511);
                ev[e] = (unsigned short)(c & 511);
                ew[e] = __uint_as_float((unsigned)(c >> 18));
            }
        }
        __syncthreads();
        for (int dd = 0; dd < 9; ++dd) {   // pointer doubling
            unsigned a = comp_a[comp_a[tid]];
            unsigned b = comp_a[comp_a[tid + 256]];
            __syncthreads();
            comp_a[tid] = a; comp_a[tid + 256] = b;
            __syncthreads();
        }
        for (int i = tid; i < 512; i += 256) comp_s[PAD(i)] = comp_a[i];
        nc = 512 - s_ecnt;                 // uniform across threads & blocks
        __syncthreads();
    }

    // ---- epilogue: leaders only ----
    if (!leader) return;

    if (tid < 64) {
        float mx = blkmax[tid];
        #pragma unroll
        for (int mm = 32; mm >= 1; mm >>= 1)
            mx = fmaxf(mx, __shfl_xor(mx, mm, 64));
        if (tid == 0) s_xdm = mx;
    }
    __syncthreads();
    const float xdm = s_xdm;
    const float lnv = latent_norm[0];
    const float sD = (m == 0) ? 1.f / xdm : 1.f / lnv;
    const float sO = (m == 0) ? 1.f / lnv : 1.f / xdm;

    if (m == 0) {                          // need ld for Om reads
        if (tid == 0) spin_magic(ldready);
        __syncthreads();
    }

    const int ne = s_ecnt;                 // 511
    float acc = 0.f;
    for (int i = tid; i < ne; i += 256) {
        float de = ew[i];
        float oe = Om[(size_t)eu[i] * N + ev[i]];
        float c = sD * de - sO * oe;
        acc = fmaf(c, c, acc);
    }
    #pragma unroll
    for (int mm = 32; mm >= 1; mm >>= 1) acc += __shfl_xor(acc, mm, 64);
    if ((tid & 63) == 0) s_red[tid >> 6] = acc;
    __syncthreads();

    if (m == 0) {
        if (tid == 0) {
            float t0 = s_red[0] + s_red[1] + s_red[2] + s_red[3];
            __hip_atomic_store(t0bits, __float_as_uint(t0), __ATOMIC_RELAXED,
                               __HIP_MEMORY_SCOPE_AGENT);
            st_rel(t0ready, MAGIC);
        }
    } else {
        float t1 = 0.f;
        if (tid == 0) t1 = s_red[0] + s_red[1] + s_red[2] + s_red[3];
        __syncthreads();                   // s_red about to be reused
        float a = ae_part[tid] + ae_part[tid + 256];
        #pragma unroll
        for (int mm = 32; mm >= 1; mm >>= 1) a += __shfl_xor(a, mm, 64);
        if ((tid & 63) == 0) s_red[tid >> 6] = a;
        __syncthreads();
        if (tid == 0) {
            float ae = s_red[0] + s_red[1] + s_red[2] + s_red[3];
            spin_magic(t0ready);
            float t0 = __uint_as_float(ld_rlx(t0bits));
            out[0] = ae * (1.f / (float)(N * DIN))
                   + (LAM * (t0 + t1)) * (1.f / (float)N);
        }
    }
}

extern "C" void kernel_launch(void* const* d_in, const int* in_sizes, int n_in,
                              void* d_out, int out_size, void* d_ws, size_t ws_size,
                              hipStream_t stream) {
    const float* x   = (const float*)d_in[0];
    // d_in[1] = label (unused)
    const float* W1  = (const float*)d_in[2];
    const float* b1  = (const float*)d_in[3];
    const float* W2  = (const float*)d_in[4];
    const float* b2  = (const float*)d_in[5];
    const float* Wm  = (const float*)d_in[6];
    const float* bm  = (const float*)d_in[7];
    const float* W3  = (const float*)d_in[8];
    const float* b3  = (const float*)d_in[9];
    const float* W4  = (const float*)d_in[10];
    const float* b4  = (const float*)d_in[11];
    const float* W5  = (const float*)d_in[12];
    const float* b5  = (const float*)d_in[13];
    const float* latent_norm = (const float*)d_in[14];

    float* ws      = (float*)d_ws;
    float* blkmax  = ws + OFF_BLKMAX;
    float* ae_part = ws + OFF_AEPART;
    float* lat     = ws + OFF_LAT;
    float* xd      = ws + OFF_XD;
    float* ld      = ws + OFF_LD;

    fused_mlp_pdistx_kernel<<<576, 256, 0, stream>>>(
        x, W1, b1, W2, b2, Wm, bm, W3, b3, W4, b4, W5, b5,
        lat, ae_part, xd, blkmax);
    mst_boruvka_kernel<<<128, 256, 0, stream>>>(
        xd, ld, lat, latent_norm, blkmax, ae_part, ws, (float*)d_out);
}